// Round 1
// baseline (624.712 us; speedup 1.0000x reference)
//
#include <hip/hip_runtime.h>
#include <hip/hip_bf16.h>

// ---------------------------------------------------------------------------
// GAT + 2 FC layers.
//   K1: xp = x @ W_gat (no bias); a_src/a_dst head dot-products (fused)
//   K2: histogram of dst (edges + self loops)
//   K3: exclusive scan -> row_ptr (single block, wave-scan based)
//   K4: scatter src ids into CSR by dst
//   K5: per-dst-node softmax-weighted aggregation (one wave per node) -> z
//   K6: z1 = z@W_fc1+b1, z2 = z@W_fc2+b2 (fused, reads z once)
// ---------------------------------------------------------------------------

// ---------------- K1: fused GEMM + attention scores ----------------
__global__ __launch_bounds__(256) void k1_gemm_att(
    const float* __restrict__ x, const float* __restrict__ W,
    const float* __restrict__ att_s, const float* __restrict__ att_d,
    float* __restrict__ xp, float* __restrict__ a_src, float* __restrict__ a_dst,
    int n)
{
    const int tid  = threadIdx.x;
    const int col  = tid & 127;
    const int half = __builtin_amdgcn_readfirstlane(tid >> 7);
    const int rb   = blockIdx.x * 32 + half * 16;
    if (rb >= n) return;

    const float* xbase = x + (size_t)rb * 128;

    float acc[16];
#pragma unroll
    for (int r = 0; r < 16; ++r) acc[r] = 0.f;

    for (int k = 0; k < 128; k += 4) {
        const float w0 = W[(k + 0) * 128 + col];
        const float w1 = W[(k + 1) * 128 + col];
        const float w2 = W[(k + 2) * 128 + col];
        const float w3 = W[(k + 3) * 128 + col];
#pragma unroll
        for (int r = 0; r < 16; ++r) {
            const float4 xv = *reinterpret_cast<const float4*>(xbase + r * 128 + k);
            acc[r] += xv.x * w0 + xv.y * w1 + xv.z * w2 + xv.w * w3;
        }
    }

    const float asw = att_s[col];   // att_src flat [8][16] == [128]
    const float adw = att_d[col];
    const int h = col >> 4;

#pragma unroll
    for (int r = 0; r < 16; ++r) {
        const int row = rb + r;
        xp[(size_t)row * 128 + col] = acc[r];
        float sv = acc[r] * asw;
        float dv = acc[r] * adw;
#pragma unroll
        for (int off = 1; off < 16; off <<= 1) {
            sv += __shfl_xor(sv, off);
            dv += __shfl_xor(dv, off);
        }
        if ((col & 15) == 0) {
            a_src[row * 8 + h] = sv;
            a_dst[row * 8 + h] = dv;
        }
    }
}

// ---------------- K2: dst histogram ----------------
__global__ __launch_bounds__(256) void k2_count(
    const int* __restrict__ ei, int* __restrict__ counts, int E, int N)
{
    const int t = blockIdx.x * blockDim.x + threadIdx.x;
    if (t < E) {
        atomicAdd(&counts[ei[E + t]], 1);       // dst row of edge_index
    } else if (t < E + N) {
        atomicAdd(&counts[t - E], 1);           // self loop
    }
}

// ---------------- K3: exclusive scan (single block, 1024 threads) ----------------
__global__ __launch_bounds__(1024) void k3_scan(
    const int* __restrict__ counts, int* __restrict__ row_ptr, int n)
{
    __shared__ int wsum[16];
    __shared__ int carry_s;
    const int tid  = threadIdx.x;
    const int lane = tid & 63;
    const int wid  = tid >> 6;
    if (tid == 0) carry_s = 0;
    __syncthreads();

    for (int base = 0; base < n; base += 4096) {
        const int idx = base + tid * 4;
        int4 v = {0, 0, 0, 0};
        if (idx + 3 < n) {
            v = *reinterpret_cast<const int4*>(&counts[idx]);
        } else {
            if (idx + 0 < n) v.x = counts[idx + 0];
            if (idx + 1 < n) v.y = counts[idx + 1];
            if (idx + 2 < n) v.z = counts[idx + 2];
            if (idx + 3 < n) v.w = counts[idx + 3];
        }
        const int s1 = v.x, s2 = s1 + v.y, s3 = s2 + v.z, s4 = s3 + v.w;

        // wave inclusive scan of per-thread totals
        int ws = s4;
#pragma unroll
        for (int off = 1; off < 64; off <<= 1) {
            const int t = __shfl_up(ws, off);
            if (lane >= off) ws += t;
        }
        if (lane == 63) wsum[wid] = ws;
        __syncthreads();

        int woff = 0;
        for (int wgi = 0; wgi < wid; ++wgi) woff += wsum[wgi];
        const int carry = carry_s;
        __syncthreads();   // all reads of carry_s/wsum done before update

        const int texcl = carry + woff + ws - s4;
        int4 o;
        o.x = texcl; o.y = texcl + s1; o.z = texcl + s2; o.w = texcl + s3;
        if (idx + 3 < n) {
            *reinterpret_cast<int4*>(&row_ptr[idx]) = o;
        } else {
            if (idx + 0 < n) row_ptr[idx + 0] = o.x;
            if (idx + 1 < n) row_ptr[idx + 1] = o.y;
            if (idx + 2 < n) row_ptr[idx + 2] = o.z;
            if (idx + 3 < n) row_ptr[idx + 3] = o.w;
        }
        if (tid == 1023) carry_s = carry + woff + ws;
        __syncthreads();
    }
    if (tid == 0) row_ptr[n] = carry_s;
}

// ---------------- K4: scatter edges into CSR ----------------
__global__ __launch_bounds__(256) void k4_scatter(
    const int* __restrict__ ei, const int* __restrict__ row_ptr,
    int* __restrict__ cursor, int* __restrict__ csr_src, int E, int N)
{
    const int t = blockIdx.x * blockDim.x + threadIdx.x;
    int s, d;
    if (t < E)            { s = ei[t]; d = ei[E + t]; }
    else if (t < E + N)   { s = t - E; d = t - E; }
    else return;
    const int pos = atomicAdd(&cursor[d], 1);
    csr_src[row_ptr[d] + pos] = s;
}

// ---------------- K5: per-node softmax aggregation (1 wave / node) ----------------
__global__ __launch_bounds__(256) void k5_aggregate(
    const float* __restrict__ xp, const float* __restrict__ a_src,
    const float* __restrict__ a_dst, const int* __restrict__ row_ptr,
    const int* __restrict__ csr_src, const float* __restrict__ b_gat,
    float* __restrict__ z, int n)
{
    const int wave = blockIdx.x * 4 + __builtin_amdgcn_readfirstlane(threadIdx.x >> 6);
    if (wave >= n) return;
    const int lane = threadIdx.x & 63;
    const int d = wave;
    const int beg = row_ptr[d];
    const int end = row_ptr[d + 1];
    const int h = lane >> 3;                 // channels 2*lane, 2*lane+1 -> head (2*lane)>>4
    const float adst = a_dst[d * 8 + h];

    // pass 1: per-head max
    float m = -1e30f;
    for (int i = beg; i < end; ++i) {
        const int s = csr_src[i];
        float v = a_src[s * 8 + h] + adst;
        v = (v > 0.f) ? v : 0.2f * v;
        m = fmaxf(m, v);
    }

    // pass 2: exp / sum / weighted accumulate
    float l = 0.f, accx = 0.f, accy = 0.f;
    for (int i = beg; i < end; ++i) {
        const int s = csr_src[i];
        float v = a_src[s * 8 + h] + adst;
        v = (v > 0.f) ? v : 0.2f * v;
        const float p = __expf(v - m);
        l += p;
        const float2 xv = *reinterpret_cast<const float2*>(&xp[(size_t)s * 128 + 2 * lane]);
        accx += p * xv.x;
        accy += p * xv.y;
    }

    const float inv = 1.0f / (l + 1e-16f);
    const float2 bg = *reinterpret_cast<const float2*>(&b_gat[2 * lane]);
    float2 o;
    o.x = accx * inv + bg.x;
    o.y = accy * inv + bg.y;
    *reinterpret_cast<float2*>(&z[(size_t)d * 128 + 2 * lane]) = o;
}

// ---------------- K6: fused FC1/FC2 ----------------
__global__ __launch_bounds__(256) void k6_fc(
    const float* __restrict__ z,
    const float* __restrict__ W1, const float* __restrict__ b1,
    const float* __restrict__ W2, const float* __restrict__ b2,
    float* __restrict__ z1, float* __restrict__ z2, int n)
{
    const int tid  = threadIdx.x;
    const int col  = tid & 127;
    const int half = __builtin_amdgcn_readfirstlane(tid >> 7);
    const int rb   = blockIdx.x * 32 + half * 16;
    if (rb >= n) return;

    const float* zbase = z + (size_t)rb * 128;

    float acc1[16], acc2[16];
#pragma unroll
    for (int r = 0; r < 16; ++r) { acc1[r] = 0.f; acc2[r] = 0.f; }

    for (int k = 0; k < 128; k += 4) {
        const float u0 = W1[(k + 0) * 128 + col];
        const float u1 = W1[(k + 1) * 128 + col];
        const float u2 = W1[(k + 2) * 128 + col];
        const float u3 = W1[(k + 3) * 128 + col];
        const float v0 = W2[(k + 0) * 128 + col];
        const float v1 = W2[(k + 1) * 128 + col];
        const float v2 = W2[(k + 2) * 128 + col];
        const float v3 = W2[(k + 3) * 128 + col];
#pragma unroll
        for (int r = 0; r < 16; ++r) {
            const float4 zv = *reinterpret_cast<const float4*>(zbase + r * 128 + k);
            acc1[r] += zv.x * u0 + zv.y * u1 + zv.z * u2 + zv.w * u3;
            acc2[r] += zv.x * v0 + zv.y * v1 + zv.z * v2 + zv.w * v3;
        }
    }

    const float bb1 = b1[col];
    const float bb2 = b2[col];
#pragma unroll
    for (int r = 0; r < 16; ++r) {
        const int row = rb + r;
        z1[(size_t)row * 128 + col] = acc1[r] + bb1;
        z2[(size_t)row * 128 + col] = acc2[r] + bb2;
    }
}

// ---------------------------------------------------------------------------
extern "C" void kernel_launch(void* const* d_in, const int* in_sizes, int n_in,
                              void* d_out, int out_size, void* d_ws, size_t ws_size,
                              hipStream_t stream)
{
    const float* x       = (const float*)d_in[0];
    const int*   ei      = (const int*)  d_in[1];
    const float* W_gat   = (const float*)d_in[2];
    const float* att_src = (const float*)d_in[3];
    const float* att_dst = (const float*)d_in[4];
    const float* b_gat   = (const float*)d_in[5];
    const float* W_fc1   = (const float*)d_in[6];
    const float* b_fc1   = (const float*)d_in[7];
    const float* W_fc2   = (const float*)d_in[8];
    const float* b_fc2   = (const float*)d_in[9];

    const int N = in_sizes[0] / 128;
    const int E = in_sizes[1] / 2;

    // workspace layout (element offsets into float/int arena)
    size_t o = 0;
    float* xp    = (float*)d_ws + o;  o += (size_t)N * 128;
    float* a_src = (float*)d_ws + o;  o += (size_t)N * 8;
    float* a_dst = (float*)d_ws + o;  o += (size_t)N * 8;
    int*   counts  = (int*)d_ws + o;  o += N;
    int*   cursor  = (int*)d_ws + o;  o += N;
    int*   row_ptr = (int*)d_ws + o;  o += N + 1;
    o = (o + 3) & ~(size_t)3;         // 16B align
    int*   csr_src = (int*)d_ws + o;  o += (size_t)E + N;

    float* z  = (float*)d_out;
    float* z1 = z  + (size_t)N * 128;
    float* z2 = z1 + (size_t)N * 128;

    // zero counts + cursor (contiguous)
    hipMemsetAsync(counts, 0, (size_t)2 * N * sizeof(int), stream);

    k1_gemm_att<<<(N + 31) / 32, 256, 0, stream>>>(x, W_gat, att_src, att_dst,
                                                   xp, a_src, a_dst, N);

    const int tot = E + N;
    k2_count<<<(tot + 255) / 256, 256, 0, stream>>>(ei, counts, E, N);
    k3_scan<<<1, 1024, 0, stream>>>(counts, row_ptr, N);
    k4_scatter<<<(tot + 255) / 256, 256, 0, stream>>>(ei, row_ptr, cursor, csr_src, E, N);

    k5_aggregate<<<(N + 3) / 4, 256, 0, stream>>>(xp, a_src, a_dst, row_ptr, csr_src,
                                                  b_gat, z, N);

    k6_fc<<<(N + 31) / 32, 256, 0, stream>>>(z, W_fc1, b_fc1, W_fc2, b_fc2, z1, z2, N);
}

// Round 2
// 513.967 us; speedup vs baseline: 1.2155x; 1.2155x over previous
//
#include <hip/hip_runtime.h>
#include <hip/hip_bf16.h>

// ---------------------------------------------------------------------------
// GAT + 2 FC layers.
//   K1: xp = x @ W_gat -> stored as bf16 (gather path); a_src/a_dst f32 (fused)
//   K2: histogram of dst (edges + self loops)
//   K3a/K3b: multi-block exclusive scan -> row_ptr
//   K4: scatter src ids into CSR by dst
//   K5: per-dst-node ONE-PASS online-softmax aggregation (1 wave/node) -> z
//   K6: z1 = z@W_fc1+b1, z2 = z@W_fc2+b2 (fused, reads z once)
// ---------------------------------------------------------------------------

#define SCAN_CHUNK 1024

// ---------------- K1: fused GEMM + attention scores ----------------
__global__ __launch_bounds__(256) void k1_gemm_att(
    const float* __restrict__ x, const float* __restrict__ W,
    const float* __restrict__ att_s, const float* __restrict__ att_d,
    __hip_bfloat16* __restrict__ xpb, float* __restrict__ a_src,
    float* __restrict__ a_dst, int n)
{
    const int tid  = threadIdx.x;
    const int col  = tid & 127;
    const int half = __builtin_amdgcn_readfirstlane(tid >> 7);
    const int rb   = blockIdx.x * 32 + half * 16;
    if (rb >= n) return;

    const float* xbase = x + (size_t)rb * 128;

    float acc[16];
#pragma unroll
    for (int r = 0; r < 16; ++r) acc[r] = 0.f;

    for (int k = 0; k < 128; k += 4) {
        const float w0 = W[(k + 0) * 128 + col];
        const float w1 = W[(k + 1) * 128 + col];
        const float w2 = W[(k + 2) * 128 + col];
        const float w3 = W[(k + 3) * 128 + col];
#pragma unroll
        for (int r = 0; r < 16; ++r) {
            const float4 xv = *reinterpret_cast<const float4*>(xbase + r * 128 + k);
            acc[r] += xv.x * w0 + xv.y * w1 + xv.z * w2 + xv.w * w3;
        }
    }

    const float asw = att_s[col];   // att_src flat [8][16] == [128]
    const float adw = att_d[col];
    const int h = col >> 4;

#pragma unroll
    for (int r = 0; r < 16; ++r) {
        const int row = rb + r;
        xpb[(size_t)row * 128 + col] = __float2bfloat16(acc[r]);
        float sv = acc[r] * asw;
        float dv = acc[r] * adw;
#pragma unroll
        for (int off = 1; off < 16; off <<= 1) {
            sv += __shfl_xor(sv, off);
            dv += __shfl_xor(dv, off);
        }
        if ((col & 15) == 0) {
            a_src[row * 8 + h] = sv;
            a_dst[row * 8 + h] = dv;
        }
    }
}

// ---------------- K2: dst histogram ----------------
__global__ __launch_bounds__(256) void k2_count(
    const int* __restrict__ ei, int* __restrict__ counts, int E, int N)
{
    const int t = blockIdx.x * blockDim.x + threadIdx.x;
    if (t < E) {
        atomicAdd(&counts[ei[E + t]], 1);       // dst row of edge_index
    } else if (t < E + N) {
        atomicAdd(&counts[t - E], 1);           // self loop
    }
}

// ---------------- K3a: per-chunk sums ----------------
__global__ __launch_bounds__(256) void k3a_chunksum(
    const int* __restrict__ counts, int* __restrict__ chunk_sums, int n)
{
    const int tid  = threadIdx.x;
    const int lane = tid & 63;
    const int wid  = tid >> 6;
    const int idx  = blockIdx.x * SCAN_CHUNK + tid * 4;

    int4 v = {0, 0, 0, 0};
    if (idx + 3 < n) {
        v = *reinterpret_cast<const int4*>(&counts[idx]);
    } else {
        if (idx + 0 < n) v.x = counts[idx + 0];
        if (idx + 1 < n) v.y = counts[idx + 1];
        if (idx + 2 < n) v.z = counts[idx + 2];
        if (idx + 3 < n) v.w = counts[idx + 3];
    }
    int s = v.x + v.y + v.z + v.w;
#pragma unroll
    for (int off = 1; off < 64; off <<= 1) s += __shfl_xor(s, off);

    __shared__ int ws[4];
    if (lane == 0) ws[wid] = s;
    __syncthreads();
    if (tid == 0) chunk_sums[blockIdx.x] = ws[0] + ws[1] + ws[2] + ws[3];
}

// ---------------- K3b: per-chunk exclusive scan + chunk prefix ----------------
__global__ __launch_bounds__(256) void k3b_scan(
    const int* __restrict__ counts, const int* __restrict__ chunk_sums,
    int* __restrict__ row_ptr, int n)
{
    const int b    = blockIdx.x;
    const int tid  = threadIdx.x;
    const int lane = tid & 63;
    const int wid  = tid >> 6;

    __shared__ int sred[4];
    __shared__ int wsum[4];

    // prefix over preceding chunk sums
    int part = 0;
    for (int j = tid; j < b; j += 256) part += chunk_sums[j];
#pragma unroll
    for (int off = 1; off < 64; off <<= 1) part += __shfl_xor(part, off);
    if (lane == 0) sred[wid] = part;
    __syncthreads();
    const int carry = sred[0] + sred[1] + sred[2] + sred[3];

    // local scan of this chunk
    const int idx = b * SCAN_CHUNK + tid * 4;
    int4 v = {0, 0, 0, 0};
    if (idx + 3 < n) {
        v = *reinterpret_cast<const int4*>(&counts[idx]);
    } else {
        if (idx + 0 < n) v.x = counts[idx + 0];
        if (idx + 1 < n) v.y = counts[idx + 1];
        if (idx + 2 < n) v.z = counts[idx + 2];
        if (idx + 3 < n) v.w = counts[idx + 3];
    }
    const int s1 = v.x, s2 = s1 + v.y, s3 = s2 + v.z, s4 = s3 + v.w;

    int ws = s4;
#pragma unroll
    for (int off = 1; off < 64; off <<= 1) {
        const int t = __shfl_up(ws, off);
        if (lane >= off) ws += t;
    }
    if (lane == 63) wsum[wid] = ws;
    __syncthreads();

    int woff = 0;
    for (int wgi = 0; wgi < wid; ++wgi) woff += wsum[wgi];

    const int texcl = carry + woff + ws - s4;
    int4 o;
    o.x = texcl; o.y = texcl + s1; o.z = texcl + s2; o.w = texcl + s3;
    if (idx + 3 < n) {
        *reinterpret_cast<int4*>(&row_ptr[idx]) = o;
    } else {
        if (idx + 0 < n) row_ptr[idx + 0] = o.x;
        if (idx + 1 < n) row_ptr[idx + 1] = o.y;
        if (idx + 2 < n) row_ptr[idx + 2] = o.z;
        if (idx + 3 < n) row_ptr[idx + 3] = o.w;
    }
    if (b == (int)gridDim.x - 1 && tid == 255) row_ptr[n] = texcl + s4;
}

// ---------------- K4: scatter edges into CSR ----------------
__global__ __launch_bounds__(256) void k4_scatter(
    const int* __restrict__ ei, const int* __restrict__ row_ptr,
    int* __restrict__ cursor, int* __restrict__ csr_src, int E, int N)
{
    const int t = blockIdx.x * blockDim.x + threadIdx.x;
    int s, d;
    if (t < E)            { s = ei[t]; d = ei[E + t]; }
    else if (t < E + N)   { s = t - E; d = t - E; }
    else return;
    const int pos = atomicAdd(&cursor[d], 1);
    csr_src[row_ptr[d] + pos] = s;
}

// ---------------- K5: one-pass online-softmax aggregation (1 wave/node) ----------------
__global__ __launch_bounds__(256) void k5_aggregate(
    const __hip_bfloat16* __restrict__ xpb, const float* __restrict__ a_src,
    const float* __restrict__ a_dst, const int* __restrict__ row_ptr,
    const int* __restrict__ csr_src, const float* __restrict__ b_gat,
    float* __restrict__ z, int n)
{
    const int wave = blockIdx.x * 4 + __builtin_amdgcn_readfirstlane(threadIdx.x >> 6);
    if (wave >= n) return;
    const int lane = threadIdx.x & 63;
    const int d = wave;
    const int beg = row_ptr[d];
    const int end = row_ptr[d + 1];
    const int h = lane >> 3;
    const float adst = a_dst[d * 8 + h];

    float m = -1e30f, l = 0.f, accx = 0.f, accy = 0.f;

    int s = (beg < end) ? csr_src[beg] : 0;
    for (int i = beg; i < end; ++i) {
        const int s_next = (i + 1 < end) ? csr_src[i + 1] : s;
        // issue gathers early
        const unsigned int xv =
            *reinterpret_cast<const unsigned int*>(xpb + (size_t)s * 128 + 2 * lane);
        float v = a_src[s * 8 + h] + adst;
        v = (v > 0.f) ? v : 0.2f * v;

        const float mn = fmaxf(m, v);
        const float sc = __expf(m - mn);
        const float p  = __expf(v - mn);
        m = mn;

        float cx, cy;
        {
            unsigned int lo = xv << 16;
            unsigned int hi = xv & 0xffff0000u;
            cx = __uint_as_float(lo);
            cy = __uint_as_float(hi);
        }
        l    = l    * sc + p;
        accx = accx * sc + p * cx;
        accy = accy * sc + p * cy;
        s = s_next;
    }

    const float inv = 1.0f / (l + 1e-16f);
    const float2 bg = *reinterpret_cast<const float2*>(&b_gat[2 * lane]);
    float2 o;
    o.x = accx * inv + bg.x;
    o.y = accy * inv + bg.y;
    *reinterpret_cast<float2*>(&z[(size_t)d * 128 + 2 * lane]) = o;
}

// ---------------- K6: fused FC1/FC2 ----------------
__global__ __launch_bounds__(256) void k6_fc(
    const float* __restrict__ z,
    const float* __restrict__ W1, const float* __restrict__ b1,
    const float* __restrict__ W2, const float* __restrict__ b2,
    float* __restrict__ z1, float* __restrict__ z2, int n)
{
    const int tid  = threadIdx.x;
    const int col  = tid & 127;
    const int half = __builtin_amdgcn_readfirstlane(tid >> 7);
    const int rb   = blockIdx.x * 32 + half * 16;
    if (rb >= n) return;

    const float* zbase = z + (size_t)rb * 128;

    float acc1[16], acc2[16];
#pragma unroll
    for (int r = 0; r < 16; ++r) { acc1[r] = 0.f; acc2[r] = 0.f; }

    for (int k = 0; k < 128; k += 4) {
        const float u0 = W1[(k + 0) * 128 + col];
        const float u1 = W1[(k + 1) * 128 + col];
        const float u2 = W1[(k + 2) * 128 + col];
        const float u3 = W1[(k + 3) * 128 + col];
        const float v0 = W2[(k + 0) * 128 + col];
        const float v1 = W2[(k + 1) * 128 + col];
        const float v2 = W2[(k + 2) * 128 + col];
        const float v3 = W2[(k + 3) * 128 + col];
#pragma unroll
        for (int r = 0; r < 16; ++r) {
            const float4 zv = *reinterpret_cast<const float4*>(zbase + r * 128 + k);
            acc1[r] += zv.x * u0 + zv.y * u1 + zv.z * u2 + zv.w * u3;
            acc2[r] += zv.x * v0 + zv.y * v1 + zv.z * v2 + zv.w * v3;
        }
    }

    const float bb1 = b1[col];
    const float bb2 = b2[col];
#pragma unroll
    for (int r = 0; r < 16; ++r) {
        const int row = rb + r;
        z1[(size_t)row * 128 + col] = acc1[r] + bb1;
        z2[(size_t)row * 128 + col] = acc2[r] + bb2;
    }
}

// ---------------------------------------------------------------------------
extern "C" void kernel_launch(void* const* d_in, const int* in_sizes, int n_in,
                              void* d_out, int out_size, void* d_ws, size_t ws_size,
                              hipStream_t stream)
{
    const float* x       = (const float*)d_in[0];
    const int*   ei      = (const int*)  d_in[1];
    const float* W_gat   = (const float*)d_in[2];
    const float* att_src = (const float*)d_in[3];
    const float* att_dst = (const float*)d_in[4];
    const float* b_gat   = (const float*)d_in[5];
    const float* W_fc1   = (const float*)d_in[6];
    const float* b_fc1   = (const float*)d_in[7];
    const float* W_fc2   = (const float*)d_in[8];
    const float* b_fc2   = (const float*)d_in[9];

    const int N = in_sizes[0] / 128;
    const int E = in_sizes[1] / 2;
    const int nchunks = (N + SCAN_CHUNK - 1) / SCAN_CHUNK;

    // workspace layout (byte offsets)
    char* w = (char*)d_ws;
    __hip_bfloat16* xpb = (__hip_bfloat16*)w;  w += (size_t)N * 128 * 2;
    float* a_src  = (float*)w;  w += (size_t)N * 8 * 4;
    float* a_dst  = (float*)w;  w += (size_t)N * 8 * 4;
    int* counts   = (int*)w;    w += (size_t)N * 4;
    int* cursor   = (int*)w;    w += (size_t)N * 4;
    int* row_ptr  = (int*)w;    w += (size_t)(N + 1) * 4;
    int* chunk_sums = (int*)w;  w += (size_t)nchunks * 4;
    w = (char*)(((size_t)w + 15) & ~(size_t)15);
    int* csr_src  = (int*)w;    w += (size_t)(E + N) * 4;

    float* z  = (float*)d_out;
    float* z1 = z  + (size_t)N * 128;
    float* z2 = z1 + (size_t)N * 128;

    // zero counts + cursor (contiguous)
    hipMemsetAsync(counts, 0, (size_t)2 * N * sizeof(int), stream);

    k1_gemm_att<<<(N + 31) / 32, 256, 0, stream>>>(x, W_gat, att_src, att_dst,
                                                   xpb, a_src, a_dst, N);

    const int tot = E + N;
    k2_count<<<(tot + 255) / 256, 256, 0, stream>>>(ei, counts, E, N);
    k3a_chunksum<<<nchunks, 256, 0, stream>>>(counts, chunk_sums, N);
    k3b_scan<<<nchunks, 256, 0, stream>>>(counts, chunk_sums, row_ptr, N);
    k4_scatter<<<(tot + 255) / 256, 256, 0, stream>>>(ei, row_ptr, cursor, csr_src, E, N);

    k5_aggregate<<<(N + 3) / 4, 256, 0, stream>>>(xpb, a_src, a_dst, row_ptr, csr_src,
                                                  b_gat, z, N);

    k6_fc<<<(N + 31) / 32, 256, 0, stream>>>(z, W_fc1, b_fc1, W_fc2, b_fc2, z1, z2, N);
}

// Round 3
// 379.561 us; speedup vs baseline: 1.6459x; 1.3541x over previous
//
#include <hip/hip_runtime.h>
#include <hip/hip_bf16.h>

// ---------------------------------------------------------------------------
// GAT + 2 FC layers, MFMA edition.
//   K0 : pre-swizzle W_gat/W_fc1/W_fc2 into bf16 MFMA B-fragment order
//   G1 : xp = x @ W_gat  (bf16 MFMA, f32 accum) -> xpb bf16
//   K1b: a_src/a_dst head dot products from xpb
//   K2 : histogram of dst (edges + self loops)
//   K3a/K3b: multi-block exclusive scan -> row_ptr
//   K4 : scatter src ids into CSR by dst
//   K5 : per-dst-node one-pass online-softmax aggregation (1 wave/node) -> z
//   G2 : z1 = z@W_fc1+b1, z2 = z@W_fc2+b2 (bf16 MFMA, fused, reads z once)
// ---------------------------------------------------------------------------

#define SCAN_CHUNK 1024

typedef __attribute__((ext_vector_type(8))) short bf16x8;
typedef __attribute__((ext_vector_type(4))) float f32x4;

static __device__ __forceinline__ short f2bf(float f) {
    __hip_bfloat16 h = __float2bfloat16(f);
    return *reinterpret_cast<short*>(&h);
}

// ---------------- K0: swizzle a 128x128 f32 weight matrix into B-frag order --
// frag (tile = cb*4+ks, lane l, elem j) = W[ks*32 + (l>>4)*8 + j][cb*16 + (l&15)]
// stored at Wswz[(tile*64 + l)*8 + j]
__global__ __launch_bounds__(256) void k0_swizzle(
    const float* __restrict__ W0, const float* __restrict__ W1,
    const float* __restrict__ W2, unsigned short* __restrict__ S0,
    unsigned short* __restrict__ S1, unsigned short* __restrict__ S2)
{
    const int t = blockIdx.x * 256 + threadIdx.x;   // 3 * 2048 lane-frags
    if (t >= 3 * 2048) return;
    const int m = t >> 11;
    const int r = t & 2047;
    const int tile = r >> 6;          // cb*4 + ks
    const int l    = r & 63;
    const int ks   = tile & 3;
    const int cb   = tile >> 2;
    const int c    = cb * 16 + (l & 15);
    const int kb   = ks * 32 + (l >> 4) * 8;
    const float* W = (m == 0) ? W0 : (m == 1) ? W1 : W2;
    unsigned short* S = (m == 0) ? S0 : (m == 1) ? S1 : S2;
    unsigned short* dst = S + ((size_t)tile * 64 + l) * 8;
#pragma unroll
    for (int j = 0; j < 8; ++j)
        dst[j] = (unsigned short)f2bf(W[(kb + j) * 128 + c]);
}

// ---------------- G1: xp = x @ W_gat via MFMA ----------------
__global__ __launch_bounds__(256) void g1_mfma(
    const float* __restrict__ x, const unsigned short* __restrict__ Wswz,
    unsigned short* __restrict__ xpb, int n)
{
    const int wid  = __builtin_amdgcn_readfirstlane(threadIdx.x >> 6);
    const int lane = threadIdx.x & 63;
    const int lr   = lane & 15;
    const int kg   = lane >> 4;
    const int rowbase = blockIdx.x * 128 + wid * 32;

    // A fragments: a[rt][ks], row = rowbase + rt*16 + lr, k = ks*32 + kg*8 + j
    bf16x8 afr[2][4];
#pragma unroll
    for (int rt = 0; rt < 2; ++rt) {
        int row = rowbase + rt * 16 + lr;
        row = (row < n) ? row : (n - 1);
        const float* rp = x + (size_t)row * 128 + kg * 8;
#pragma unroll
        for (int ks = 0; ks < 4; ++ks) {
            const float4 v0 = *reinterpret_cast<const float4*>(rp + ks * 32);
            const float4 v1 = *reinterpret_cast<const float4*>(rp + ks * 32 + 4);
            bf16x8 a;
            a[0] = f2bf(v0.x); a[1] = f2bf(v0.y); a[2] = f2bf(v0.z); a[3] = f2bf(v0.w);
            a[4] = f2bf(v1.x); a[5] = f2bf(v1.y); a[6] = f2bf(v1.z); a[7] = f2bf(v1.w);
            afr[rt][ks] = a;
        }
    }

    f32x4 acc[2][8] = {};
#pragma unroll
    for (int cb = 0; cb < 8; ++cb) {
        const unsigned short* bp = Wswz + ((size_t)(cb * 4) * 64 + lane) * 8;
        bf16x8 bfr[4];
#pragma unroll
        for (int ks = 0; ks < 4; ++ks)
            bfr[ks] = *reinterpret_cast<const bf16x8*>(bp + (size_t)ks * 512);
#pragma unroll
        for (int ks = 0; ks < 4; ++ks) {
            acc[0][cb] = __builtin_amdgcn_mfma_f32_16x16x32_bf16(afr[0][ks], bfr[ks], acc[0][cb], 0, 0, 0);
            acc[1][cb] = __builtin_amdgcn_mfma_f32_16x16x32_bf16(afr[1][ks], bfr[ks], acc[1][cb], 0, 0, 0);
        }
    }

    // D: col = cb*16 + lr, row = rowbase + rt*16 + kg*4 + reg
#pragma unroll
    for (int rt = 0; rt < 2; ++rt) {
#pragma unroll
        for (int reg = 0; reg < 4; ++reg) {
            const int row = rowbase + rt * 16 + kg * 4 + reg;
            if (row < n) {
                unsigned short* op = xpb + (size_t)row * 128 + lr;
#pragma unroll
                for (int cb = 0; cb < 8; ++cb)
                    op[cb * 16] = (unsigned short)f2bf(acc[rt][cb][reg]);
            }
        }
    }
}

// ---------------- K1b: attention score dot products from xpb ----------------
__global__ __launch_bounds__(256) void k1b_att(
    const unsigned short* __restrict__ xpb, const float* __restrict__ att_s,
    const float* __restrict__ att_d, float* __restrict__ a_src,
    float* __restrict__ a_dst, int n)
{
    const int tid  = threadIdx.x;
    const int col  = tid & 127;
    const int half = __builtin_amdgcn_readfirstlane(tid >> 7);
    const int rb   = blockIdx.x * 32 + half * 16;
    if (rb >= n) return;
    const float asw = att_s[col];
    const float adw = att_d[col];
    const int h = col >> 4;
#pragma unroll 4
    for (int r = 0; r < 16; ++r) {
        const int row = rb + r;
        if (row >= n) break;
        const unsigned int u = (unsigned int)xpb[(size_t)row * 128 + col] << 16;
        const float v = __uint_as_float(u);
        float sv = v * asw;
        float dv = v * adw;
#pragma unroll
        for (int off = 1; off < 16; off <<= 1) {
            sv += __shfl_xor(sv, off);
            dv += __shfl_xor(dv, off);
        }
        if ((col & 15) == 0) {
            a_src[row * 8 + h] = sv;
            a_dst[row * 8 + h] = dv;
        }
    }
}

// ---------------- K2: dst histogram ----------------
__global__ __launch_bounds__(256) void k2_count(
    const int* __restrict__ ei, int* __restrict__ counts, int E, int N)
{
    const int t = blockIdx.x * blockDim.x + threadIdx.x;
    if (t < E) {
        atomicAdd(&counts[ei[E + t]], 1);
    } else if (t < E + N) {
        atomicAdd(&counts[t - E], 1);
    }
}

// ---------------- K3a: per-chunk sums ----------------
__global__ __launch_bounds__(256) void k3a_chunksum(
    const int* __restrict__ counts, int* __restrict__ chunk_sums, int n)
{
    const int tid  = threadIdx.x;
    const int lane = tid & 63;
    const int wid  = tid >> 6;
    const int idx  = blockIdx.x * SCAN_CHUNK + tid * 4;

    int4 v = {0, 0, 0, 0};
    if (idx + 3 < n) {
        v = *reinterpret_cast<const int4*>(&counts[idx]);
    } else {
        if (idx + 0 < n) v.x = counts[idx + 0];
        if (idx + 1 < n) v.y = counts[idx + 1];
        if (idx + 2 < n) v.z = counts[idx + 2];
        if (idx + 3 < n) v.w = counts[idx + 3];
    }
    int s = v.x + v.y + v.z + v.w;
#pragma unroll
    for (int off = 1; off < 64; off <<= 1) s += __shfl_xor(s, off);

    __shared__ int ws[4];
    if (lane == 0) ws[wid] = s;
    __syncthreads();
    if (tid == 0) chunk_sums[blockIdx.x] = ws[0] + ws[1] + ws[2] + ws[3];
}

// ---------------- K3b: per-chunk exclusive scan + chunk prefix ----------------
__global__ __launch_bounds__(256) void k3b_scan(
    const int* __restrict__ counts, const int* __restrict__ chunk_sums,
    int* __restrict__ row_ptr, int n)
{
    const int b    = blockIdx.x;
    const int tid  = threadIdx.x;
    const int lane = tid & 63;
    const int wid  = tid >> 6;

    __shared__ int sred[4];
    __shared__ int wsum[4];

    int part = 0;
    for (int j = tid; j < b; j += 256) part += chunk_sums[j];
#pragma unroll
    for (int off = 1; off < 64; off <<= 1) part += __shfl_xor(part, off);
    if (lane == 0) sred[wid] = part;
    __syncthreads();
    const int carry = sred[0] + sred[1] + sred[2] + sred[3];

    const int idx = b * SCAN_CHUNK + tid * 4;
    int4 v = {0, 0, 0, 0};
    if (idx + 3 < n) {
        v = *reinterpret_cast<const int4*>(&counts[idx]);
    } else {
        if (idx + 0 < n) v.x = counts[idx + 0];
        if (idx + 1 < n) v.y = counts[idx + 1];
        if (idx + 2 < n) v.z = counts[idx + 2];
        if (idx + 3 < n) v.w = counts[idx + 3];
    }
    const int s1 = v.x, s2 = s1 + v.y, s3 = s2 + v.z, s4 = s3 + v.w;

    int ws = s4;
#pragma unroll
    for (int off = 1; off < 64; off <<= 1) {
        const int t = __shfl_up(ws, off);
        if (lane >= off) ws += t;
    }
    if (lane == 63) wsum[wid] = ws;
    __syncthreads();

    int woff = 0;
    for (int wgi = 0; wgi < wid; ++wgi) woff += wsum[wgi];

    const int texcl = carry + woff + ws - s4;
    int4 o;
    o.x = texcl; o.y = texcl + s1; o.z = texcl + s2; o.w = texcl + s3;
    if (idx + 3 < n) {
        *reinterpret_cast<int4*>(&row_ptr[idx]) = o;
    } else {
        if (idx + 0 < n) row_ptr[idx + 0] = o.x;
        if (idx + 1 < n) row_ptr[idx + 1] = o.y;
        if (idx + 2 < n) row_ptr[idx + 2] = o.z;
        if (idx + 3 < n) row_ptr[idx + 3] = o.w;
    }
    if (b == (int)gridDim.x - 1 && tid == 255) row_ptr[n] = texcl + s4;
}

// ---------------- K4: scatter edges into CSR ----------------
__global__ __launch_bounds__(256) void k4_scatter(
    const int* __restrict__ ei, const int* __restrict__ row_ptr,
    int* __restrict__ cursor, int* __restrict__ csr_src, int E, int N)
{
    const int t = blockIdx.x * blockDim.x + threadIdx.x;
    int s, d;
    if (t < E)            { s = ei[t]; d = ei[E + t]; }
    else if (t < E + N)   { s = t - E; d = t - E; }
    else return;
    const int pos = atomicAdd(&cursor[d], 1);
    csr_src[row_ptr[d] + pos] = s;
}

// ---------------- K5: one-pass online-softmax aggregation (1 wave/node) ------
__global__ __launch_bounds__(256) void k5_aggregate(
    const unsigned short* __restrict__ xpb, const float* __restrict__ a_src,
    const float* __restrict__ a_dst, const int* __restrict__ row_ptr,
    const int* __restrict__ csr_src, const float* __restrict__ b_gat,
    float* __restrict__ z, int n)
{
    const int wave = blockIdx.x * 4 + __builtin_amdgcn_readfirstlane(threadIdx.x >> 6);
    if (wave >= n) return;
    const int lane = threadIdx.x & 63;
    const int d = wave;
    const int beg = row_ptr[d];
    const int end = row_ptr[d + 1];
    const int h = lane >> 3;
    const float adst = a_dst[d * 8 + h];

    float m = -1e30f, l = 0.f, accx = 0.f, accy = 0.f;

    int s = (beg < end) ? csr_src[beg] : 0;
    for (int i = beg; i < end; ++i) {
        const int s_next = (i + 1 < end) ? csr_src[i + 1] : s;
        const unsigned int xv =
            *reinterpret_cast<const unsigned int*>(xpb + (size_t)s * 128 + 2 * lane);
        float v = a_src[s * 8 + h] + adst;
        v = (v > 0.f) ? v : 0.2f * v;

        const float mn = fmaxf(m, v);
        const float sc = __expf(m - mn);
        const float p  = __expf(v - mn);
        m = mn;

        const float cx = __uint_as_float(xv << 16);
        const float cy = __uint_as_float(xv & 0xffff0000u);
        l    = l    * sc + p;
        accx = accx * sc + p * cx;
        accy = accy * sc + p * cy;
        s = s_next;
    }

    const float inv = 1.0f / (l + 1e-16f);
    const float2 bg = *reinterpret_cast<const float2*>(&b_gat[2 * lane]);
    float2 o;
    o.x = accx * inv + bg.x;
    o.y = accy * inv + bg.y;
    *reinterpret_cast<float2*>(&z[(size_t)d * 128 + 2 * lane]) = o;
}

// ---------------- G2: z1 = z@W1+b1, z2 = z@W2+b2 via MFMA ----------------
__global__ __launch_bounds__(256) void g2_mfma_fc(
    const float* __restrict__ z,
    const unsigned short* __restrict__ S1, const unsigned short* __restrict__ S2,
    const float* __restrict__ b1, const float* __restrict__ b2,
    float* __restrict__ z1, float* __restrict__ z2, int n)
{
    const int wid  = __builtin_amdgcn_readfirstlane(threadIdx.x >> 6);
    const int lane = threadIdx.x & 63;
    const int lr   = lane & 15;
    const int kg   = lane >> 4;
    const int rowbase = blockIdx.x * 128 + wid * 32;

    bf16x8 afr[2][4];
#pragma unroll
    for (int rt = 0; rt < 2; ++rt) {
        int row = rowbase + rt * 16 + lr;
        row = (row < n) ? row : (n - 1);
        const float* rp = z + (size_t)row * 128 + kg * 8;
#pragma unroll
        for (int ks = 0; ks < 4; ++ks) {
            const float4 v0 = *reinterpret_cast<const float4*>(rp + ks * 32);
            const float4 v1 = *reinterpret_cast<const float4*>(rp + ks * 32 + 4);
            bf16x8 a;
            a[0] = f2bf(v0.x); a[1] = f2bf(v0.y); a[2] = f2bf(v0.z); a[3] = f2bf(v0.w);
            a[4] = f2bf(v1.x); a[5] = f2bf(v1.y); a[6] = f2bf(v1.z); a[7] = f2bf(v1.w);
            afr[rt][ks] = a;
        }
    }

    f32x4 acc1[2][8] = {};
    f32x4 acc2[2][8] = {};
#pragma unroll
    for (int cb = 0; cb < 8; ++cb) {
        const unsigned short* bp1 = S1 + ((size_t)(cb * 4) * 64 + lane) * 8;
        const unsigned short* bp2 = S2 + ((size_t)(cb * 4) * 64 + lane) * 8;
        bf16x8 f1[4], f2v[4];
#pragma unroll
        for (int ks = 0; ks < 4; ++ks) {
            f1[ks]  = *reinterpret_cast<const bf16x8*>(bp1 + (size_t)ks * 512);
            f2v[ks] = *reinterpret_cast<const bf16x8*>(bp2 + (size_t)ks * 512);
        }
#pragma unroll
        for (int ks = 0; ks < 4; ++ks) {
            acc1[0][cb] = __builtin_amdgcn_mfma_f32_16x16x32_bf16(afr[0][ks], f1[ks],  acc1[0][cb], 0, 0, 0);
            acc1[1][cb] = __builtin_amdgcn_mfma_f32_16x16x32_bf16(afr[1][ks], f1[ks],  acc1[1][cb], 0, 0, 0);
            acc2[0][cb] = __builtin_amdgcn_mfma_f32_16x16x32_bf16(afr[0][ks], f2v[ks], acc2[0][cb], 0, 0, 0);
            acc2[1][cb] = __builtin_amdgcn_mfma_f32_16x16x32_bf16(afr[1][ks], f2v[ks], acc2[1][cb], 0, 0, 0);
        }
    }

    float bb1[8], bb2[8];
#pragma unroll
    for (int cb = 0; cb < 8; ++cb) { bb1[cb] = b1[cb * 16 + lr]; bb2[cb] = b2[cb * 16 + lr]; }

#pragma unroll
    for (int rt = 0; rt < 2; ++rt) {
#pragma unroll
        for (int reg = 0; reg < 4; ++reg) {
            const int row = rowbase + rt * 16 + kg * 4 + reg;
            if (row < n) {
                float* o1 = z1 + (size_t)row * 128 + lr;
                float* o2 = z2 + (size_t)row * 128 + lr;
#pragma unroll
                for (int cb = 0; cb < 8; ++cb) {
                    o1[cb * 16] = acc1[rt][cb][reg] + bb1[cb];
                    o2[cb * 16] = acc2[rt][cb][reg] + bb2[cb];
                }
            }
        }
    }
}

// ---------------------------------------------------------------------------
extern "C" void kernel_launch(void* const* d_in, const int* in_sizes, int n_in,
                              void* d_out, int out_size, void* d_ws, size_t ws_size,
                              hipStream_t stream)
{
    const float* x       = (const float*)d_in[0];
    const int*   ei      = (const int*)  d_in[1];
    const float* W_gat   = (const float*)d_in[2];
    const float* att_src = (const float*)d_in[3];
    const float* att_dst = (const float*)d_in[4];
    const float* b_gat   = (const float*)d_in[5];
    const float* W_fc1   = (const float*)d_in[6];
    const float* b_fc1   = (const float*)d_in[7];
    const float* W_fc2   = (const float*)d_in[8];
    const float* b_fc2   = (const float*)d_in[9];

    const int N = in_sizes[0] / 128;
    const int E = in_sizes[1] / 2;
    const int nchunks = (N + SCAN_CHUNK - 1) / SCAN_CHUNK;

    char* w = (char*)d_ws;
    unsigned short* xpb = (unsigned short*)w;  w += (size_t)N * 128 * 2;
    float* a_src  = (float*)w;  w += (size_t)N * 8 * 4;
    float* a_dst  = (float*)w;  w += (size_t)N * 8 * 4;
    int* counts   = (int*)w;    w += (size_t)N * 4;
    int* cursor   = (int*)w;    w += (size_t)N * 4;
    int* row_ptr  = (int*)w;    w += (size_t)(N + 1) * 4;
    int* chunk_sums = (int*)w;  w += (size_t)nchunks * 4;
    w = (char*)(((size_t)w + 15) & ~(size_t)15);
    unsigned short* S0 = (unsigned short*)w; w += 16384 * 2;
    unsigned short* S1 = (unsigned short*)w; w += 16384 * 2;
    unsigned short* S2 = (unsigned short*)w; w += 16384 * 2;
    w = (char*)(((size_t)w + 15) & ~(size_t)15);
    int* csr_src  = (int*)w;    w += (size_t)(E + N) * 4;

    float* z  = (float*)d_out;
    float* z1 = z  + (size_t)N * 128;
    float* z2 = z1 + (size_t)N * 128;

    hipMemsetAsync(counts, 0, (size_t)2 * N * sizeof(int), stream);

    k0_swizzle<<<(3 * 2048 + 255) / 256, 256, 0, stream>>>(W_gat, W_fc1, W_fc2, S0, S1, S2);

    g1_mfma<<<(N + 127) / 128, 256, 0, stream>>>(x, S0, xpb, N);
    k1b_att<<<(N + 31) / 32, 256, 0, stream>>>(xpb, att_src, att_dst, a_src, a_dst, N);

    const int tot = E + N;
    k2_count<<<(tot + 255) / 256, 256, 0, stream>>>(ei, counts, E, N);
    k3a_chunksum<<<nchunks, 256, 0, stream>>>(counts, chunk_sums, N);
    k3b_scan<<<nchunks, 256, 0, stream>>>(counts, chunk_sums, row_ptr, N);
    k4_scatter<<<(tot + 255) / 256, 256, 0, stream>>>(ei, row_ptr, cursor, csr_src, E, N);

    k5_aggregate<<<(N + 3) / 4, 256, 0, stream>>>(xpb, a_src, a_dst, row_ptr, csr_src,
                                                  b_gat, z, N);

    g2_mfma_fc<<<(N + 127) / 128, 256, 0, stream>>>(z, S1, S2, b_fc1, b_fc2, z1, z2, N);
}

// Round 4
// 352.738 us; speedup vs baseline: 1.7710x; 1.0760x over previous
//
#include <hip/hip_runtime.h>
#include <hip/hip_bf16.h>

// ---------------------------------------------------------------------------
// GAT + 2 FC layers, MFMA edition.
//   K0 : pre-swizzle W_gat/W_fc1/W_fc2 into bf16 MFMA B-fragment order
//   G1 : xp = x @ W_gat  (bf16 MFMA, f32 accum) -> xpb bf16
//   K1b: a_src/a_dst head dot products from xpb
//   K2 : histogram of dst (edges + self loops)
//   K3a/K3b: multi-block exclusive scan -> row_ptr (k3b also seeds cursor)
//   K4 : scatter src ids into CSR by dst (atomic on cursor = absolute pos)
//   K5 : per-dst-node softmax aggregation, UNSTABILIZED exp, unroll x4
//   G2 : z1 = z@W_fc1+b1, z2 = z@W_fc2+b2 (bf16 MFMA, fused, reads z once)
// ---------------------------------------------------------------------------

#define SCAN_CHUNK 1024

typedef __attribute__((ext_vector_type(8))) short bf16x8;
typedef __attribute__((ext_vector_type(4))) float f32x4;

static __device__ __forceinline__ short f2bf(float f) {
    __hip_bfloat16 h = __float2bfloat16(f);
    return *reinterpret_cast<short*>(&h);
}

// ---------------- K0: swizzle a 128x128 f32 weight matrix into B-frag order --
__global__ __launch_bounds__(256) void k0_swizzle(
    const float* __restrict__ W0, const float* __restrict__ W1,
    const float* __restrict__ W2, unsigned short* __restrict__ S0,
    unsigned short* __restrict__ S1, unsigned short* __restrict__ S2)
{
    const int t = blockIdx.x * 256 + threadIdx.x;   // 3 * 2048 lane-frags
    if (t >= 3 * 2048) return;
    const int m = t >> 11;
    const int r = t & 2047;
    const int tile = r >> 6;          // cb*4 + ks
    const int l    = r & 63;
    const int ks   = tile & 3;
    const int cb   = tile >> 2;
    const int c    = cb * 16 + (l & 15);
    const int kb   = ks * 32 + (l >> 4) * 8;
    const float* W = (m == 0) ? W0 : (m == 1) ? W1 : W2;
    unsigned short* S = (m == 0) ? S0 : (m == 1) ? S1 : S2;
    unsigned short* dst = S + ((size_t)tile * 64 + l) * 8;
#pragma unroll
    for (int j = 0; j < 8; ++j)
        dst[j] = (unsigned short)f2bf(W[(kb + j) * 128 + c]);
}

// ---------------- G1: xp = x @ W_gat via MFMA ----------------
__global__ __launch_bounds__(256) void g1_mfma(
    const float* __restrict__ x, const unsigned short* __restrict__ Wswz,
    unsigned short* __restrict__ xpb, int n)
{
    const int wid  = __builtin_amdgcn_readfirstlane(threadIdx.x >> 6);
    const int lane = threadIdx.x & 63;
    const int lr   = lane & 15;
    const int kg   = lane >> 4;
    const int rowbase = blockIdx.x * 128 + wid * 32;

    bf16x8 afr[2][4];
#pragma unroll
    for (int rt = 0; rt < 2; ++rt) {
        int row = rowbase + rt * 16 + lr;
        row = (row < n) ? row : (n - 1);
        const float* rp = x + (size_t)row * 128 + kg * 8;
#pragma unroll
        for (int ks = 0; ks < 4; ++ks) {
            const float4 v0 = *reinterpret_cast<const float4*>(rp + ks * 32);
            const float4 v1 = *reinterpret_cast<const float4*>(rp + ks * 32 + 4);
            bf16x8 a;
            a[0] = f2bf(v0.x); a[1] = f2bf(v0.y); a[2] = f2bf(v0.z); a[3] = f2bf(v0.w);
            a[4] = f2bf(v1.x); a[5] = f2bf(v1.y); a[6] = f2bf(v1.z); a[7] = f2bf(v1.w);
            afr[rt][ks] = a;
        }
    }

    f32x4 acc[2][8] = {};
#pragma unroll
    for (int cb = 0; cb < 8; ++cb) {
        const unsigned short* bp = Wswz + ((size_t)(cb * 4) * 64 + lane) * 8;
        bf16x8 bfr[4];
#pragma unroll
        for (int ks = 0; ks < 4; ++ks)
            bfr[ks] = *reinterpret_cast<const bf16x8*>(bp + (size_t)ks * 512);
#pragma unroll
        for (int ks = 0; ks < 4; ++ks) {
            acc[0][cb] = __builtin_amdgcn_mfma_f32_16x16x32_bf16(afr[0][ks], bfr[ks], acc[0][cb], 0, 0, 0);
            acc[1][cb] = __builtin_amdgcn_mfma_f32_16x16x32_bf16(afr[1][ks], bfr[ks], acc[1][cb], 0, 0, 0);
        }
    }

#pragma unroll
    for (int rt = 0; rt < 2; ++rt) {
#pragma unroll
        for (int reg = 0; reg < 4; ++reg) {
            const int row = rowbase + rt * 16 + kg * 4 + reg;
            if (row < n) {
                unsigned short* op = xpb + (size_t)row * 128 + lr;
#pragma unroll
                for (int cb = 0; cb < 8; ++cb)
                    op[cb * 16] = (unsigned short)f2bf(acc[rt][cb][reg]);
            }
        }
    }
}

// ---------------- K1b: attention score dot products from xpb ----------------
__global__ __launch_bounds__(256) void k1b_att(
    const unsigned short* __restrict__ xpb, const float* __restrict__ att_s,
    const float* __restrict__ att_d, float* __restrict__ a_src,
    float* __restrict__ a_dst, int n)
{
    const int tid  = threadIdx.x;
    const int col  = tid & 127;
    const int half = __builtin_amdgcn_readfirstlane(tid >> 7);
    const int rb   = blockIdx.x * 32 + half * 16;
    if (rb >= n) return;
    const float asw = att_s[col];
    const float adw = att_d[col];
    const int h = col >> 4;
#pragma unroll 4
    for (int r = 0; r < 16; ++r) {
        const int row = rb + r;
        if (row >= n) break;
        const unsigned int u = (unsigned int)xpb[(size_t)row * 128 + col] << 16;
        const float v = __uint_as_float(u);
        float sv = v * asw;
        float dv = v * adw;
#pragma unroll
        for (int off = 1; off < 16; off <<= 1) {
            sv += __shfl_xor(sv, off);
            dv += __shfl_xor(dv, off);
        }
        if ((col & 15) == 0) {
            a_src[row * 8 + h] = sv;
            a_dst[row * 8 + h] = dv;
        }
    }
}

// ---------------- K2: dst histogram ----------------
__global__ __launch_bounds__(256) void k2_count(
    const int* __restrict__ ei, int* __restrict__ counts, int E, int N)
{
    const int t = blockIdx.x * blockDim.x + threadIdx.x;
    if (t < E) {
        atomicAdd(&counts[ei[E + t]], 1);
    } else if (t < E + N) {
        atomicAdd(&counts[t - E], 1);
    }
}

// ---------------- K3a: per-chunk sums ----------------
__global__ __launch_bounds__(256) void k3a_chunksum(
    const int* __restrict__ counts, int* __restrict__ chunk_sums, int n)
{
    const int tid  = threadIdx.x;
    const int lane = tid & 63;
    const int wid  = tid >> 6;
    const int idx  = blockIdx.x * SCAN_CHUNK + tid * 4;

    int4 v = {0, 0, 0, 0};
    if (idx + 3 < n) {
        v = *reinterpret_cast<const int4*>(&counts[idx]);
    } else {
        if (idx + 0 < n) v.x = counts[idx + 0];
        if (idx + 1 < n) v.y = counts[idx + 1];
        if (idx + 2 < n) v.z = counts[idx + 2];
        if (idx + 3 < n) v.w = counts[idx + 3];
    }
    int s = v.x + v.y + v.z + v.w;
#pragma unroll
    for (int off = 1; off < 64; off <<= 1) s += __shfl_xor(s, off);

    __shared__ int ws[4];
    if (lane == 0) ws[wid] = s;
    __syncthreads();
    if (tid == 0) chunk_sums[blockIdx.x] = ws[0] + ws[1] + ws[2] + ws[3];
}

// ---------------- K3b: per-chunk exclusive scan + chunk prefix ----------------
__global__ __launch_bounds__(256) void k3b_scan(
    const int* __restrict__ counts, const int* __restrict__ chunk_sums,
    int* __restrict__ row_ptr, int* __restrict__ cursor, int n)
{
    const int b    = blockIdx.x;
    const int tid  = threadIdx.x;
    const int lane = tid & 63;
    const int wid  = tid >> 6;

    __shared__ int sred[4];
    __shared__ int wsum[4];

    int part = 0;
    for (int j = tid; j < b; j += 256) part += chunk_sums[j];
#pragma unroll
    for (int off = 1; off < 64; off <<= 1) part += __shfl_xor(part, off);
    if (lane == 0) sred[wid] = part;
    __syncthreads();
    const int carry = sred[0] + sred[1] + sred[2] + sred[3];

    const int idx = b * SCAN_CHUNK + tid * 4;
    int4 v = {0, 0, 0, 0};
    if (idx + 3 < n) {
        v = *reinterpret_cast<const int4*>(&counts[idx]);
    } else {
        if (idx + 0 < n) v.x = counts[idx + 0];
        if (idx + 1 < n) v.y = counts[idx + 1];
        if (idx + 2 < n) v.z = counts[idx + 2];
        if (idx + 3 < n) v.w = counts[idx + 3];
    }
    const int s1 = v.x, s2 = s1 + v.y, s3 = s2 + v.z, s4 = s3 + v.w;

    int ws = s4;
#pragma unroll
    for (int off = 1; off < 64; off <<= 1) {
        const int t = __shfl_up(ws, off);
        if (lane >= off) ws += t;
    }
    if (lane == 63) wsum[wid] = ws;
    __syncthreads();

    int woff = 0;
    for (int wgi = 0; wgi < wid; ++wgi) woff += wsum[wgi];

    const int texcl = carry + woff + ws - s4;
    int4 o;
    o.x = texcl; o.y = texcl + s1; o.z = texcl + s2; o.w = texcl + s3;
    if (idx + 3 < n) {
        *reinterpret_cast<int4*>(&row_ptr[idx]) = o;
        *reinterpret_cast<int4*>(&cursor[idx])  = o;
    } else {
        if (idx + 0 < n) { row_ptr[idx + 0] = o.x; cursor[idx + 0] = o.x; }
        if (idx + 1 < n) { row_ptr[idx + 1] = o.y; cursor[idx + 1] = o.y; }
        if (idx + 2 < n) { row_ptr[idx + 2] = o.z; cursor[idx + 2] = o.z; }
        if (idx + 3 < n) { row_ptr[idx + 3] = o.w; cursor[idx + 3] = o.w; }
    }
    if (b == (int)gridDim.x - 1 && tid == 255) row_ptr[n] = texcl + s4;
}

// ---------------- K4: scatter edges into CSR (cursor holds absolute pos) -----
__global__ __launch_bounds__(256) void k4_scatter(
    const int* __restrict__ ei, int* __restrict__ cursor,
    int* __restrict__ csr_src, int E, int N)
{
    const int t = blockIdx.x * blockDim.x + threadIdx.x;
    int s, d;
    if (t < E)            { s = ei[t]; d = ei[E + t]; }
    else if (t < E + N)   { s = t - E; d = t - E; }
    else return;
    const int pos = atomicAdd(&cursor[d], 1);
    csr_src[pos] = s;
}

// ---------------- K5: softmax aggregation, unstabilized exp, unroll x4 -------
__global__ __launch_bounds__(256) void k5_aggregate(
    const unsigned short* __restrict__ xpb, const float* __restrict__ a_src,
    const float* __restrict__ a_dst, const int* __restrict__ row_ptr,
    const int* __restrict__ csr_src, const float* __restrict__ b_gat,
    float* __restrict__ z, int n)
{
    const int wave = blockIdx.x * 4 + __builtin_amdgcn_readfirstlane(threadIdx.x >> 6);
    if (wave >= n) return;
    const int lane = threadIdx.x & 63;
    const int d = wave;
    const int beg = row_ptr[d];
    const int end = row_ptr[d + 1];
    const int h = lane >> 3;
    const float adst = a_dst[d * 8 + h];
    const int co = 2 * lane;

    float l0 = 0.f, l1 = 0.f;
    float ax0 = 0.f, ay0 = 0.f, ax1 = 0.f, ay1 = 0.f;

    int i = beg;
    for (; i + 4 <= end; i += 4) {
        const int s0 = csr_src[i + 0];
        const int s1 = csr_src[i + 1];
        const int s2 = csr_src[i + 2];
        const int s3 = csr_src[i + 3];
        const unsigned int xv0 = *reinterpret_cast<const unsigned int*>(xpb + (size_t)s0 * 128 + co);
        const unsigned int xv1 = *reinterpret_cast<const unsigned int*>(xpb + (size_t)s1 * 128 + co);
        const unsigned int xv2 = *reinterpret_cast<const unsigned int*>(xpb + (size_t)s2 * 128 + co);
        const unsigned int xv3 = *reinterpret_cast<const unsigned int*>(xpb + (size_t)s3 * 128 + co);
        float v0 = a_src[s0 * 8 + h] + adst;
        float v1 = a_src[s1 * 8 + h] + adst;
        float v2 = a_src[s2 * 8 + h] + adst;
        float v3 = a_src[s3 * 8 + h] + adst;
        v0 = (v0 > 0.f) ? v0 : 0.2f * v0;
        v1 = (v1 > 0.f) ? v1 : 0.2f * v1;
        v2 = (v2 > 0.f) ? v2 : 0.2f * v2;
        v3 = (v3 > 0.f) ? v3 : 0.2f * v3;
        const float p0 = __expf(v0);
        const float p1 = __expf(v1);
        const float p2 = __expf(v2);
        const float p3 = __expf(v3);
        l0 += p0 + p1;
        l1 += p2 + p3;
        ax0 = fmaf(p0, __uint_as_float(xv0 << 16), ax0);
        ay0 = fmaf(p0, __uint_as_float(xv0 & 0xffff0000u), ay0);
        ax1 = fmaf(p1, __uint_as_float(xv1 << 16), ax1);
        ay1 = fmaf(p1, __uint_as_float(xv1 & 0xffff0000u), ay1);
        ax0 = fmaf(p2, __uint_as_float(xv2 << 16), ax0);
        ay0 = fmaf(p2, __uint_as_float(xv2 & 0xffff0000u), ay0);
        ax1 = fmaf(p3, __uint_as_float(xv3 << 16), ax1);
        ay1 = fmaf(p3, __uint_as_float(xv3 & 0xffff0000u), ay1);
    }
    for (; i < end; ++i) {
        const int s = csr_src[i];
        const unsigned int xv = *reinterpret_cast<const unsigned int*>(xpb + (size_t)s * 128 + co);
        float v = a_src[s * 8 + h] + adst;
        v = (v > 0.f) ? v : 0.2f * v;
        const float p = __expf(v);
        l0 += p;
        ax0 = fmaf(p, __uint_as_float(xv << 16), ax0);
        ay0 = fmaf(p, __uint_as_float(xv & 0xffff0000u), ay0);
    }

    const float inv = 1.0f / (l0 + l1 + 1e-16f);
    const float2 bg = *reinterpret_cast<const float2*>(&b_gat[co]);
    float2 o;
    o.x = (ax0 + ax1) * inv + bg.x;
    o.y = (ay0 + ay1) * inv + bg.y;
    *reinterpret_cast<float2*>(&z[(size_t)d * 128 + co]) = o;
}

// ---------------- G2: z1 = z@W1+b1, z2 = z@W2+b2 via MFMA ----------------
__global__ __launch_bounds__(256) void g2_mfma_fc(
    const float* __restrict__ z,
    const unsigned short* __restrict__ S1, const unsigned short* __restrict__ S2,
    const float* __restrict__ b1, const float* __restrict__ b2,
    float* __restrict__ z1, float* __restrict__ z2, int n)
{
    const int wid  = __builtin_amdgcn_readfirstlane(threadIdx.x >> 6);
    const int lane = threadIdx.x & 63;
    const int lr   = lane & 15;
    const int kg   = lane >> 4;
    const int rowbase = blockIdx.x * 128 + wid * 32;

    bf16x8 afr[2][4];
#pragma unroll
    for (int rt = 0; rt < 2; ++rt) {
        int row = rowbase + rt * 16 + lr;
        row = (row < n) ? row : (n - 1);
        const float* rp = z + (size_t)row * 128 + kg * 8;
#pragma unroll
        for (int ks = 0; ks < 4; ++ks) {
            const float4 v0 = *reinterpret_cast<const float4*>(rp + ks * 32);
            const float4 v1 = *reinterpret_cast<const float4*>(rp + ks * 32 + 4);
            bf16x8 a;
            a[0] = f2bf(v0.x); a[1] = f2bf(v0.y); a[2] = f2bf(v0.z); a[3] = f2bf(v0.w);
            a[4] = f2bf(v1.x); a[5] = f2bf(v1.y); a[6] = f2bf(v1.z); a[7] = f2bf(v1.w);
            afr[rt][ks] = a;
        }
    }

    f32x4 acc1[2][8] = {};
    f32x4 acc2[2][8] = {};
#pragma unroll
    for (int cb = 0; cb < 8; ++cb) {
        const unsigned short* bp1 = S1 + ((size_t)(cb * 4) * 64 + lane) * 8;
        const unsigned short* bp2 = S2 + ((size_t)(cb * 4) * 64 + lane) * 8;
        bf16x8 f1[4], f2v[4];
#pragma unroll
        for (int ks = 0; ks < 4; ++ks) {
            f1[ks]  = *reinterpret_cast<const bf16x8*>(bp1 + (size_t)ks * 512);
            f2v[ks] = *reinterpret_cast<const bf16x8*>(bp2 + (size_t)ks * 512);
        }
#pragma unroll
        for (int ks = 0; ks < 4; ++ks) {
            acc1[0][cb] = __builtin_amdgcn_mfma_f32_16x16x32_bf16(afr[0][ks], f1[ks],  acc1[0][cb], 0, 0, 0);
            acc1[1][cb] = __builtin_amdgcn_mfma_f32_16x16x32_bf16(afr[1][ks], f1[ks],  acc1[1][cb], 0, 0, 0);
            acc2[0][cb] = __builtin_amdgcn_mfma_f32_16x16x32_bf16(afr[0][ks], f2v[ks], acc2[0][cb], 0, 0, 0);
            acc2[1][cb] = __builtin_amdgcn_mfma_f32_16x16x32_bf16(afr[1][ks], f2v[ks], acc2[1][cb], 0, 0, 0);
        }
    }

    float bb1[8], bb2[8];
#pragma unroll
    for (int cb = 0; cb < 8; ++cb) { bb1[cb] = b1[cb * 16 + lr]; bb2[cb] = b2[cb * 16 + lr]; }

#pragma unroll
    for (int rt = 0; rt < 2; ++rt) {
#pragma unroll
        for (int reg = 0; reg < 4; ++reg) {
            const int row = rowbase + rt * 16 + kg * 4 + reg;
            if (row < n) {
                float* o1 = z1 + (size_t)row * 128 + lr;
                float* o2 = z2 + (size_t)row * 128 + lr;
#pragma unroll
                for (int cb = 0; cb < 8; ++cb) {
                    o1[cb * 16] = acc1[rt][cb][reg] + bb1[cb];
                    o2[cb * 16] = acc2[rt][cb][reg] + bb2[cb];
                }
            }
        }
    }
}

// ---------------------------------------------------------------------------
extern "C" void kernel_launch(void* const* d_in, const int* in_sizes, int n_in,
                              void* d_out, int out_size, void* d_ws, size_t ws_size,
                              hipStream_t stream)
{
    const float* x       = (const float*)d_in[0];
    const int*   ei      = (const int*)  d_in[1];
    const float* W_gat   = (const float*)d_in[2];
    const float* att_src = (const float*)d_in[3];
    const float* att_dst = (const float*)d_in[4];
    const float* b_gat   = (const float*)d_in[5];
    const float* W_fc1   = (const float*)d_in[6];
    const float* b_fc1   = (const float*)d_in[7];
    const float* W_fc2   = (const float*)d_in[8];
    const float* b_fc2   = (const float*)d_in[9];

    const int N = in_sizes[0] / 128;
    const int E = in_sizes[1] / 2;
    const int nchunks = (N + SCAN_CHUNK - 1) / SCAN_CHUNK;

    char* w = (char*)d_ws;
    unsigned short* xpb = (unsigned short*)w;  w += (size_t)N * 128 * 2;
    float* a_src  = (float*)w;  w += (size_t)N * 8 * 4;
    float* a_dst  = (float*)w;  w += (size_t)N * 8 * 4;
    int* counts   = (int*)w;    w += (size_t)N * 4;
    int* cursor   = (int*)w;    w += (size_t)N * 4;
    int* row_ptr  = (int*)w;    w += (size_t)(N + 1) * 4;
    int* chunk_sums = (int*)w;  w += (size_t)nchunks * 4;
    w = (char*)(((size_t)w + 15) & ~(size_t)15);
    unsigned short* S0 = (unsigned short*)w; w += 16384 * 2;
    unsigned short* S1 = (unsigned short*)w; w += 16384 * 2;
    unsigned short* S2 = (unsigned short*)w; w += 16384 * 2;
    w = (char*)(((size_t)w + 15) & ~(size_t)15);
    int* csr_src  = (int*)w;    w += (size_t)(E + N) * 4;

    float* z  = (float*)d_out;
    float* z1 = z  + (size_t)N * 128;
    float* z2 = z1 + (size_t)N * 128;

    hipMemsetAsync(counts, 0, (size_t)N * sizeof(int), stream);

    k0_swizzle<<<(3 * 2048 + 255) / 256, 256, 0, stream>>>(W_gat, W_fc1, W_fc2, S0, S1, S2);

    g1_mfma<<<(N + 127) / 128, 256, 0, stream>>>(x, S0, xpb, N);
    k1b_att<<<(N + 31) / 32, 256, 0, stream>>>(xpb, att_src, att_dst, a_src, a_dst, N);

    const int tot = E + N;
    k2_count<<<(tot + 255) / 256, 256, 0, stream>>>(ei, counts, E, N);
    k3a_chunksum<<<nchunks, 256, 0, stream>>>(counts, chunk_sums, N);
    k3b_scan<<<nchunks, 256, 0, stream>>>(counts, chunk_sums, row_ptr, cursor, N);
    k4_scatter<<<(tot + 255) / 256, 256, 0, stream>>>(ei, cursor, csr_src, E, N);

    k5_aggregate<<<(N + 3) / 4, 256, 0, stream>>>(xpb, a_src, a_dst, row_ptr, csr_src,
                                                  b_gat, z, N);

    g2_mfma_fc<<<(N + 127) / 128, 256, 0, stream>>>(z, S1, S2, b_fc1, b_fc2, z1, z2, N);
}

// Round 5
// 238.878 us; speedup vs baseline: 2.6152x; 1.4766x over previous
//
#include <hip/hip_runtime.h>
#include <hip/hip_bf16.h>

// ---------------------------------------------------------------------------
// GAT + 2 FC layers, MFMA + atomic-free CSR build.
//   K0 : pre-swizzle W_gat/W_fc1/W_fc2 into bf16 MFMA B-fragment order
//   G1 : xp = x @ W_gat  (bf16 MFMA, f32 accum) -> xpb bf16
//   K1b: a_src/a_dst head dot products from xpb
//   P1 : per-block LDS histogram over 256 coarse buckets (dst>>9) -> M
//   P2a: per-bucket exclusive scan of M over blocks -> col_total
//   P2b: exclusive scan of col_total -> bucket_ptr (+ row_ptr[N]=tot)
//   P3 : scatter (s,d) pairs into bucket segments (LDS rank, no glb atomics)
//   P4 : per-bucket: LDS hist over 512 dsts -> row_ptr + csr_src scatter
//   K5 : per-dst-node softmax aggregation, unstabilized exp, unroll x4
//   G2 : z1 = z@W_fc1+b1, z2 = z@W_fc2+b2 (bf16 MFMA, fused, reads z once)
// ---------------------------------------------------------------------------

#define NBUCK  256
#define BSHIFT 9
#define BNODES 512
#define IPB    8192   // items per block for P1/P3 (256 thr x 32)

typedef __attribute__((ext_vector_type(8))) short bf16x8;
typedef __attribute__((ext_vector_type(4))) float f32x4;

static __device__ __forceinline__ short f2bf(float f) {
    __hip_bfloat16 h = __float2bfloat16(f);
    return *reinterpret_cast<short*>(&h);
}

// ---------------- K0: swizzle 128x128 f32 weights into B-frag order ----------
__global__ __launch_bounds__(256) void k0_swizzle(
    const float* __restrict__ W0, const float* __restrict__ W1,
    const float* __restrict__ W2, unsigned short* __restrict__ S0,
    unsigned short* __restrict__ S1, unsigned short* __restrict__ S2)
{
    const int t = blockIdx.x * 256 + threadIdx.x;   // 3 * 2048 lane-frags
    if (t >= 3 * 2048) return;
    const int m = t >> 11;
    const int r = t & 2047;
    const int tile = r >> 6;          // cb*4 + ks
    const int l    = r & 63;
    const int ks   = tile & 3;
    const int cb   = tile >> 2;
    const int c    = cb * 16 + (l & 15);
    const int kb   = ks * 32 + (l >> 4) * 8;
    const float* W = (m == 0) ? W0 : (m == 1) ? W1 : W2;
    unsigned short* S = (m == 0) ? S0 : (m == 1) ? S1 : S2;
    unsigned short* dst = S + ((size_t)tile * 64 + l) * 8;
#pragma unroll
    for (int j = 0; j < 8; ++j)
        dst[j] = (unsigned short)f2bf(W[(kb + j) * 128 + c]);
}

// ---------------- G1: xp = x @ W_gat via MFMA ----------------
__global__ __launch_bounds__(256) void g1_mfma(
    const float* __restrict__ x, const unsigned short* __restrict__ Wswz,
    unsigned short* __restrict__ xpb, int n)
{
    const int wid  = __builtin_amdgcn_readfirstlane(threadIdx.x >> 6);
    const int lane = threadIdx.x & 63;
    const int lr   = lane & 15;
    const int kg   = lane >> 4;
    const int rowbase = blockIdx.x * 128 + wid * 32;

    bf16x8 afr[2][4];
#pragma unroll
    for (int rt = 0; rt < 2; ++rt) {
        int row = rowbase + rt * 16 + lr;
        row = (row < n) ? row : (n - 1);
        const float* rp = x + (size_t)row * 128 + kg * 8;
#pragma unroll
        for (int ks = 0; ks < 4; ++ks) {
            const float4 v0 = *reinterpret_cast<const float4*>(rp + ks * 32);
            const float4 v1 = *reinterpret_cast<const float4*>(rp + ks * 32 + 4);
            bf16x8 a;
            a[0] = f2bf(v0.x); a[1] = f2bf(v0.y); a[2] = f2bf(v0.z); a[3] = f2bf(v0.w);
            a[4] = f2bf(v1.x); a[5] = f2bf(v1.y); a[6] = f2bf(v1.z); a[7] = f2bf(v1.w);
            afr[rt][ks] = a;
        }
    }

    f32x4 acc[2][8] = {};
#pragma unroll
    for (int cb = 0; cb < 8; ++cb) {
        const unsigned short* bp = Wswz + ((size_t)(cb * 4) * 64 + lane) * 8;
        bf16x8 bfr[4];
#pragma unroll
        for (int ks = 0; ks < 4; ++ks)
            bfr[ks] = *reinterpret_cast<const bf16x8*>(bp + (size_t)ks * 512);
#pragma unroll
        for (int ks = 0; ks < 4; ++ks) {
            acc[0][cb] = __builtin_amdgcn_mfma_f32_16x16x32_bf16(afr[0][ks], bfr[ks], acc[0][cb], 0, 0, 0);
            acc[1][cb] = __builtin_amdgcn_mfma_f32_16x16x32_bf16(afr[1][ks], bfr[ks], acc[1][cb], 0, 0, 0);
        }
    }

#pragma unroll
    for (int rt = 0; rt < 2; ++rt) {
#pragma unroll
        for (int reg = 0; reg < 4; ++reg) {
            const int row = rowbase + rt * 16 + kg * 4 + reg;
            if (row < n) {
                unsigned short* op = xpb + (size_t)row * 128 + lr;
#pragma unroll
                for (int cb = 0; cb < 8; ++cb)
                    op[cb * 16] = (unsigned short)f2bf(acc[rt][cb][reg]);
            }
        }
    }
}

// ---------------- K1b: attention score dot products from xpb ----------------
__global__ __launch_bounds__(256) void k1b_att(
    const unsigned short* __restrict__ xpb, const float* __restrict__ att_s,
    const float* __restrict__ att_d, float* __restrict__ a_src,
    float* __restrict__ a_dst, int n)
{
    const int tid  = threadIdx.x;
    const int col  = tid & 127;
    const int half = __builtin_amdgcn_readfirstlane(tid >> 7);
    const int rb   = blockIdx.x * 32 + half * 16;
    if (rb >= n) return;
    const float asw = att_s[col];
    const float adw = att_d[col];
    const int h = col >> 4;
#pragma unroll 4
    for (int r = 0; r < 16; ++r) {
        const int row = rb + r;
        if (row >= n) break;
        const unsigned int u = (unsigned int)xpb[(size_t)row * 128 + col] << 16;
        const float v = __uint_as_float(u);
        float sv = v * asw;
        float dv = v * adw;
#pragma unroll
        for (int off = 1; off < 16; off <<= 1) {
            sv += __shfl_xor(sv, off);
            dv += __shfl_xor(dv, off);
        }
        if ((col & 15) == 0) {
            a_src[row * 8 + h] = sv;
            a_dst[row * 8 + h] = dv;
        }
    }
}

// ---------------- P1: coarse-bucket histogram per block ----------------
__global__ __launch_bounds__(256) void p1_hist(
    const int* __restrict__ ei, int* __restrict__ M, int E, int N, int nblk)
{
    __shared__ int h[NBUCK];
    const int tid = threadIdx.x;
    for (int k = tid; k < NBUCK; k += 256) h[k] = 0;
    __syncthreads();

    const int tot = E + N;
    const int base = blockIdx.x * IPB;
    const int lim = (base + IPB < tot) ? base + IPB : tot;
    for (int j = base + tid; j < lim; j += 256) {
        const int d = (j < E) ? ei[E + j] : (j - E);
        atomicAdd(&h[d >> BSHIFT], 1);
    }
    __syncthreads();
    for (int k = tid; k < NBUCK; k += 256)
        M[(size_t)k * nblk + blockIdx.x] = h[k];
}

// ---------------- P2a: per-bucket exclusive scan of M over blocks ------------
__global__ __launch_bounds__(256) void p2a_colscan(
    int* __restrict__ M, int* __restrict__ col_total, int nblk)
{
    const int b    = blockIdx.x;
    const int tid  = threadIdx.x;
    const int lane = tid & 63;
    const int wid  = tid >> 6;
    __shared__ int wsum[4];

    int carry = 0;
    for (int base = 0; base < nblk; base += 256) {
        const int idx = base + tid;
        const int v = (idx < nblk) ? M[(size_t)b * nblk + idx] : 0;
        int ws = v;
#pragma unroll
        for (int off = 1; off < 64; off <<= 1) {
            const int t = __shfl_up(ws, off);
            if (lane >= off) ws += t;
        }
        if (lane == 63) wsum[wid] = ws;
        __syncthreads();
        int woff = 0;
        for (int w2 = 0; w2 < wid; ++w2) woff += wsum[w2];
        const int alltot = wsum[0] + wsum[1] + wsum[2] + wsum[3];
        if (idx < nblk) M[(size_t)b * nblk + idx] = carry + woff + ws - v;
        carry += alltot;
        __syncthreads();
    }
    if (tid == 0) col_total[b] = carry;
}

// ---------------- P2b: scan col_total -> bucket_ptr; row_ptr[N]=tot ----------
__global__ __launch_bounds__(NBUCK) void p2b_bucketptr(
    const int* __restrict__ col_total, int* __restrict__ bucket_ptr,
    int* __restrict__ row_ptr, int N)
{
    const int tid  = threadIdx.x;
    const int lane = tid & 63;
    const int wid  = tid >> 6;
    __shared__ int wsum[4];

    const int v = col_total[tid];
    int ws = v;
#pragma unroll
    for (int off = 1; off < 64; off <<= 1) {
        const int t = __shfl_up(ws, off);
        if (lane >= off) ws += t;
    }
    if (lane == 63) wsum[wid] = ws;
    __syncthreads();
    int woff = 0;
    for (int w2 = 0; w2 < wid; ++w2) woff += wsum[w2];
    const int excl = woff + ws - v;
    bucket_ptr[tid] = excl;
    if (tid == NBUCK - 1) {
        bucket_ptr[NBUCK] = excl + v;
        row_ptr[N] = excl + v;
    }
}

// ---------------- P3: scatter (s,d) pairs into bucket segments ---------------
__global__ __launch_bounds__(256) void p3_scatter(
    const int* __restrict__ ei, const int* __restrict__ M,
    const int* __restrict__ bucket_ptr, int2* __restrict__ pairs,
    int E, int N, int nblk)
{
    __shared__ int lcnt[NBUCK];
    const int tid = threadIdx.x;
    for (int k = tid; k < NBUCK; k += 256) lcnt[k] = 0;
    __syncthreads();

    const int tot = E + N;
    const int base = blockIdx.x * IPB;
    const int lim = (base + IPB < tot) ? base + IPB : tot;
    for (int j = base + tid; j < lim; j += 256) {
        int s, d;
        if (j < E) { s = ei[j]; d = ei[E + j]; }
        else       { s = j - E; d = s; }
        const int b = d >> BSHIFT;
        const int r = atomicAdd(&lcnt[b], 1);
        const int pos = bucket_ptr[b] + M[(size_t)b * nblk + blockIdx.x] + r;
        pairs[pos] = make_int2(s, d);
    }
}

// ---------------- P4: per-bucket row_ptr + csr scatter ----------------
__global__ __launch_bounds__(256) void p4_finalize(
    const int2* __restrict__ pairs, const int* __restrict__ bucket_ptr,
    int* __restrict__ row_ptr, int* __restrict__ csr_src, int N)
{
    const int b     = blockIdx.x;
    const int node0 = b << BSHIFT;
    const int beg   = bucket_ptr[b];
    const int end   = bucket_ptr[b + 1];
    const int tid   = threadIdx.x;
    const int lane  = tid & 63;
    const int wid   = tid >> 6;

    __shared__ int hist[BNODES];
    __shared__ int exc[BNODES];
    __shared__ int cnt2[BNODES];
    __shared__ int wsum[4];

    for (int k = tid; k < BNODES; k += 256) { hist[k] = 0; cnt2[k] = 0; }
    __syncthreads();

    for (int i = beg + tid; i < end; i += 256)
        atomicAdd(&hist[pairs[i].y - node0], 1);
    __syncthreads();

    // block exclusive scan of hist[512]: each thread owns elements 2t, 2t+1
    const int a0 = hist[2 * tid];
    const int a1 = hist[2 * tid + 1];
    const int s  = a0 + a1;
    int ws = s;
#pragma unroll
    for (int off = 1; off < 64; off <<= 1) {
        const int t = __shfl_up(ws, off);
        if (lane >= off) ws += t;
    }
    if (lane == 63) wsum[wid] = ws;
    __syncthreads();
    int woff = 0;
    for (int w2 = 0; w2 < wid; ++w2) woff += wsum[w2];
    const int e0 = woff + ws - s;
    exc[2 * tid]     = e0;
    exc[2 * tid + 1] = e0 + a0;
    __syncthreads();

    for (int k = tid; k < BNODES; k += 256) {
        const int node = node0 + k;
        if (node < N) row_ptr[node] = beg + exc[k];
    }
    for (int i = beg + tid; i < end; i += 256) {
        const int2 p = pairs[i];
        const int dl = p.y - node0;
        const int r  = atomicAdd(&cnt2[dl], 1);
        csr_src[beg + exc[dl] + r] = p.x;
    }
}

// ---------------- K5: softmax aggregation, unstabilized exp, unroll x4 -------
__global__ __launch_bounds__(256) void k5_aggregate(
    const unsigned short* __restrict__ xpb, const float* __restrict__ a_src,
    const float* __restrict__ a_dst, const int* __restrict__ row_ptr,
    const int* __restrict__ csr_src, const float* __restrict__ b_gat,
    float* __restrict__ z, int n)
{
    const int wave = blockIdx.x * 4 + __builtin_amdgcn_readfirstlane(threadIdx.x >> 6);
    if (wave >= n) return;
    const int lane = threadIdx.x & 63;
    const int d = wave;
    const int beg = row_ptr[d];
    const int end = row_ptr[d + 1];
    const int h = lane >> 3;
    const float adst = a_dst[d * 8 + h];
    const int co = 2 * lane;

    float l0 = 0.f, l1 = 0.f;
    float ax0 = 0.f, ay0 = 0.f, ax1 = 0.f, ay1 = 0.f;

    int i = beg;
    for (; i + 4 <= end; i += 4) {
        const int s0 = csr_src[i + 0];
        const int s1 = csr_src[i + 1];
        const int s2 = csr_src[i + 2];
        const int s3 = csr_src[i + 3];
        const unsigned int xv0 = *reinterpret_cast<const unsigned int*>(xpb + (size_t)s0 * 128 + co);
        const unsigned int xv1 = *reinterpret_cast<const unsigned int*>(xpb + (size_t)s1 * 128 + co);
        const unsigned int xv2 = *reinterpret_cast<const unsigned int*>(xpb + (size_t)s2 * 128 + co);
        const unsigned int xv3 = *reinterpret_cast<const unsigned int*>(xpb + (size_t)s3 * 128 + co);
        float v0 = a_src[s0 * 8 + h] + adst;
        float v1 = a_src[s1 * 8 + h] + adst;
        float v2 = a_src[s2 * 8 + h] + adst;
        float v3 = a_src[s3 * 8 + h] + adst;
        v0 = (v0 > 0.f) ? v0 : 0.2f * v0;
        v1 = (v1 > 0.f) ? v1 : 0.2f * v1;
        v2 = (v2 > 0.f) ? v2 : 0.2f * v2;
        v3 = (v3 > 0.f) ? v3 : 0.2f * v3;
        const float p0 = __expf(v0);
        const float p1 = __expf(v1);
        const float p2 = __expf(v2);
        const float p3 = __expf(v3);
        l0 += p0 + p1;
        l1 += p2 + p3;
        ax0 = fmaf(p0, __uint_as_float(xv0 << 16), ax0);
        ay0 = fmaf(p0, __uint_as_float(xv0 & 0xffff0000u), ay0);
        ax1 = fmaf(p1, __uint_as_float(xv1 << 16), ax1);
        ay1 = fmaf(p1, __uint_as_float(xv1 & 0xffff0000u), ay1);
        ax0 = fmaf(p2, __uint_as_float(xv2 << 16), ax0);
        ay0 = fmaf(p2, __uint_as_float(xv2 & 0xffff0000u), ay0);
        ax1 = fmaf(p3, __uint_as_float(xv3 << 16), ax1);
        ay1 = fmaf(p3, __uint_as_float(xv3 & 0xffff0000u), ay1);
    }
    for (; i < end; ++i) {
        const int s = csr_src[i];
        const unsigned int xv = *reinterpret_cast<const unsigned int*>(xpb + (size_t)s * 128 + co);
        float v = a_src[s * 8 + h] + adst;
        v = (v > 0.f) ? v : 0.2f * v;
        const float p = __expf(v);
        l0 += p;
        ax0 = fmaf(p, __uint_as_float(xv << 16), ax0);
        ay0 = fmaf(p, __uint_as_float(xv & 0xffff0000u), ay0);
    }

    const float inv = 1.0f / (l0 + l1 + 1e-16f);
    const float2 bg = *reinterpret_cast<const float2*>(&b_gat[co]);
    float2 o;
    o.x = (ax0 + ax1) * inv + bg.x;
    o.y = (ay0 + ay1) * inv + bg.y;
    *reinterpret_cast<float2*>(&z[(size_t)d * 128 + co]) = o;
}

// ---------------- G2: z1 = z@W1+b1, z2 = z@W2+b2 via MFMA ----------------
__global__ __launch_bounds__(256) void g2_mfma_fc(
    const float* __restrict__ z,
    const unsigned short* __restrict__ S1, const unsigned short* __restrict__ S2,
    const float* __restrict__ b1, const float* __restrict__ b2,
    float* __restrict__ z1, float* __restrict__ z2, int n)
{
    const int wid  = __builtin_amdgcn_readfirstlane(threadIdx.x >> 6);
    const int lane = threadIdx.x & 63;
    const int lr   = lane & 15;
    const int kg   = lane >> 4;
    const int rowbase = blockIdx.x * 128 + wid * 32;

    bf16x8 afr[2][4];
#pragma unroll
    for (int rt = 0; rt < 2; ++rt) {
        int row = rowbase + rt * 16 + lr;
        row = (row < n) ? row : (n - 1);
        const float* rp = z + (size_t)row * 128 + kg * 8;
#pragma unroll
        for (int ks = 0; ks < 4; ++ks) {
            const float4 v0 = *reinterpret_cast<const float4*>(rp + ks * 32);
            const float4 v1 = *reinterpret_cast<const float4*>(rp + ks * 32 + 4);
            bf16x8 a;
            a[0] = f2bf(v0.x); a[1] = f2bf(v0.y); a[2] = f2bf(v0.z); a[3] = f2bf(v0.w);
            a[4] = f2bf(v1.x); a[5] = f2bf(v1.y); a[6] = f2bf(v1.z); a[7] = f2bf(v1.w);
            afr[rt][ks] = a;
        }
    }

    f32x4 acc1[2][8] = {};
    f32x4 acc2[2][8] = {};
#pragma unroll
    for (int cb = 0; cb < 8; ++cb) {
        const unsigned short* bp1 = S1 + ((size_t)(cb * 4) * 64 + lane) * 8;
        const unsigned short* bp2 = S2 + ((size_t)(cb * 4) * 64 + lane) * 8;
        bf16x8 f1[4], f2v[4];
#pragma unroll
        for (int ks = 0; ks < 4; ++ks) {
            f1[ks]  = *reinterpret_cast<const bf16x8*>(bp1 + (size_t)ks * 512);
            f2v[ks] = *reinterpret_cast<const bf16x8*>(bp2 + (size_t)ks * 512);
        }
#pragma unroll
        for (int ks = 0; ks < 4; ++ks) {
            acc1[0][cb] = __builtin_amdgcn_mfma_f32_16x16x32_bf16(afr[0][ks], f1[ks],  acc1[0][cb], 0, 0, 0);
            acc1[1][cb] = __builtin_amdgcn_mfma_f32_16x16x32_bf16(afr[1][ks], f1[ks],  acc1[1][cb], 0, 0, 0);
            acc2[0][cb] = __builtin_amdgcn_mfma_f32_16x16x32_bf16(afr[0][ks], f2v[ks], acc2[0][cb], 0, 0, 0);
            acc2[1][cb] = __builtin_amdgcn_mfma_f32_16x16x32_bf16(afr[1][ks], f2v[ks], acc2[1][cb], 0, 0, 0);
        }
    }

    float bb1[8], bb2[8];
#pragma unroll
    for (int cb = 0; cb < 8; ++cb) { bb1[cb] = b1[cb * 16 + lr]; bb2[cb] = b2[cb * 16 + lr]; }

#pragma unroll
    for (int rt = 0; rt < 2; ++rt) {
#pragma unroll
        for (int reg = 0; reg < 4; ++reg) {
            const int row = rowbase + rt * 16 + kg * 4 + reg;
            if (row < n) {
                float* o1 = z1 + (size_t)row * 128 + lr;
                float* o2 = z2 + (size_t)row * 128 + lr;
#pragma unroll
                for (int cb = 0; cb < 8; ++cb) {
                    o1[cb * 16] = acc1[rt][cb][reg] + bb1[cb];
                    o2[cb * 16] = acc2[rt][cb][reg] + bb2[cb];
                }
            }
        }
    }
}

// ---------------------------------------------------------------------------
extern "C" void kernel_launch(void* const* d_in, const int* in_sizes, int n_in,
                              void* d_out, int out_size, void* d_ws, size_t ws_size,
                              hipStream_t stream)
{
    const float* x       = (const float*)d_in[0];
    const int*   ei      = (const int*)  d_in[1];
    const float* W_gat   = (const float*)d_in[2];
    const float* att_src = (const float*)d_in[3];
    const float* att_dst = (const float*)d_in[4];
    const float* b_gat   = (const float*)d_in[5];
    const float* W_fc1   = (const float*)d_in[6];
    const float* b_fc1   = (const float*)d_in[7];
    const float* W_fc2   = (const float*)d_in[8];
    const float* b_fc2   = (const float*)d_in[9];

    const int N = in_sizes[0] / 128;
    const int E = in_sizes[1] / 2;
    const int tot = E + N;
    const int nblk = (tot + IPB - 1) / IPB;
    const int nbuck_used = (N + BNODES - 1) >> BSHIFT;

    char* w = (char*)d_ws;
    unsigned short* xpb = (unsigned short*)w;  w += (size_t)N * 128 * 2;
    float* a_src  = (float*)w;  w += (size_t)N * 8 * 4;
    float* a_dst  = (float*)w;  w += (size_t)N * 8 * 4;
    int* row_ptr  = (int*)w;    w += (size_t)(N + 1) * 4;
    w = (char*)(((size_t)w + 15) & ~(size_t)15);
    unsigned short* S0 = (unsigned short*)w; w += 16384 * 2;
    unsigned short* S1 = (unsigned short*)w; w += 16384 * 2;
    unsigned short* S2 = (unsigned short*)w; w += 16384 * 2;
    int* M          = (int*)w;  w += (size_t)nblk * NBUCK * 4;
    int* col_total  = (int*)w;  w += NBUCK * 4;
    int* bucket_ptr = (int*)w;  w += (NBUCK + 1) * 4;
    w = (char*)(((size_t)w + 15) & ~(size_t)15);
    int2* pairs   = (int2*)w;   w += (size_t)tot * 8;
    int* csr_src  = (int*)w;    w += (size_t)tot * 4;

    float* z  = (float*)d_out;
    float* z1 = z  + (size_t)N * 128;
    float* z2 = z1 + (size_t)N * 128;

    k0_swizzle<<<(3 * 2048 + 255) / 256, 256, 0, stream>>>(W_gat, W_fc1, W_fc2, S0, S1, S2);

    g1_mfma<<<(N + 127) / 128, 256, 0, stream>>>(x, S0, xpb, N);
    k1b_att<<<(N + 31) / 32, 256, 0, stream>>>(xpb, att_src, att_dst, a_src, a_dst, N);

    p1_hist<<<nblk, 256, 0, stream>>>(ei, M, E, N, nblk);
    p2a_colscan<<<NBUCK, 256, 0, stream>>>(M, col_total, nblk);
    p2b_bucketptr<<<1, NBUCK, 0, stream>>>(col_total, bucket_ptr, row_ptr, N);
    p3_scatter<<<nblk, 256, 0, stream>>>(ei, M, bucket_ptr, pairs, E, N, nblk);
    p4_finalize<<<nbuck_used, 256, 0, stream>>>(pairs, bucket_ptr, row_ptr, csr_src, N);

    k5_aggregate<<<(N + 3) / 4, 256, 0, stream>>>(xpb, a_src, a_dst, row_ptr, csr_src,
                                                  b_gat, z, N);

    g2_mfma_fc<<<(N + 127) / 128, 256, 0, stream>>>(z, S1, S2, b_fc1, b_fc2, z1, z2, N);
}

// Round 6
// 218.733 us; speedup vs baseline: 2.8560x; 1.0921x over previous
//
#include <hip/hip_runtime.h>
#include <hip/hip_bf16.h>

// ---------------------------------------------------------------------------
// GAT + 2 FC layers, MFMA + atomic-free CSR build.
//   K0 : swizzle W_gat/W_fc1/W_fc2 into bf16 MFMA B-frag order; also compute
//        WA = [W_gat@B_att_src | W_gat@B_att_dst] (128x16) swizzled -> Sa
//   G1 : xp = x @ W_gat (bf16 MFMA) -> xpb bf16; a_src/a_dst via Sa MFMA block
//   P1 : per-block LDS histogram over 256 coarse buckets (dst>>9) -> M
//   P2a: per-bucket exclusive scan of M over blocks -> col_total
//   P2b: exclusive scan of col_total -> bucket_ptr (+ row_ptr[N]=tot)
//   P3 : scatter packed (src|dl<<17) into bucket segments (LDS rank)
//   P4 : per-bucket: LDS hist over 512 dsts -> row_ptr + csr_src scatter
//   K5 : per-dst softmax aggregation (unstabilized exp, unroll x4) -> z f32
//        + zb bf16 (packed) for G2's A operand
//   G2 : z1 = z@W_fc1+b1, z2 = z@W_fc2+b2 (bf16 MFMA, A from zb)
// ---------------------------------------------------------------------------

#define NBUCK  256
#define BSHIFT 9
#define BNODES 512
#define IPB    8192

typedef __attribute__((ext_vector_type(8))) short bf16x8;
typedef __attribute__((ext_vector_type(4))) float f32x4;

static __device__ __forceinline__ short f2bf(float f) {
    __hip_bfloat16 h = __float2bfloat16(f);
    return *reinterpret_cast<short*>(&h);
}

// ---------------- K0: weight swizzles + WA precompute ----------------
__global__ __launch_bounds__(256) void k0_swizzle(
    const float* __restrict__ W0, const float* __restrict__ W1,
    const float* __restrict__ W2, const float* __restrict__ att_s,
    const float* __restrict__ att_d, unsigned short* __restrict__ S0,
    unsigned short* __restrict__ S1, unsigned short* __restrict__ S2,
    unsigned short* __restrict__ Sa)
{
    const int t = blockIdx.x * 256 + threadIdx.x;
    if (t < 3 * 2048) {
        const int m = t >> 11;
        const int r = t & 2047;
        const int tile = r >> 6;          // cb*4 + ks
        const int l    = r & 63;
        const int ks   = tile & 3;
        const int cb   = tile >> 2;
        const int c    = cb * 16 + (l & 15);
        const int kb   = ks * 32 + (l >> 4) * 8;
        const float* W = (m == 0) ? W0 : (m == 1) ? W1 : W2;
        unsigned short* S = (m == 0) ? S0 : (m == 1) ? S1 : S2;
        unsigned short* dst = S + ((size_t)tile * 64 + l) * 8;
#pragma unroll
        for (int j = 0; j < 8; ++j)
            dst[j] = (unsigned short)f2bf(W[(kb + j) * 128 + c]);
    } else if (t < 3 * 2048 + 256) {
        // Sa: tile ks, lane l, col hp = l&15 (hp<8: src head hp; else dst head hp-8)
        const int r  = t - 3 * 2048;
        const int ks = r >> 6;
        const int l  = r & 63;
        const int hp = l & 15;
        const int h  = hp & 7;
        const float* av = (hp < 8) ? (att_s + h * 16) : (att_d + h * 16);
        unsigned short* dst = Sa + ((size_t)ks * 64 + l) * 8;
#pragma unroll
        for (int j = 0; j < 8; ++j) {
            const int k = ks * 32 + (l >> 4) * 8 + j;
            float acc = 0.f;
#pragma unroll
            for (int u = 0; u < 16; ++u)
                acc += W0[k * 128 + h * 16 + u] * av[u];
            dst[j] = (unsigned short)f2bf(acc);
        }
    }
}

// ---------------- G1: xp = x @ W_gat via MFMA (+ attention scores) ----------
__global__ __launch_bounds__(256) void g1_mfma(
    const float* __restrict__ x, const unsigned short* __restrict__ Wswz,
    const unsigned short* __restrict__ Sa, unsigned short* __restrict__ xpb,
    float* __restrict__ a_src, float* __restrict__ a_dst, int n)
{
    const int wid  = __builtin_amdgcn_readfirstlane(threadIdx.x >> 6);
    const int lane = threadIdx.x & 63;
    const int lr   = lane & 15;
    const int kg   = lane >> 4;
    const int rowbase = blockIdx.x * 128 + wid * 32;

    bf16x8 afr[2][4];
#pragma unroll
    for (int rt = 0; rt < 2; ++rt) {
        int row = rowbase + rt * 16 + lr;
        row = (row < n) ? row : (n - 1);
        const float* rp = x + (size_t)row * 128 + kg * 8;
#pragma unroll
        for (int ks = 0; ks < 4; ++ks) {
            const float4 v0 = *reinterpret_cast<const float4*>(rp + ks * 32);
            const float4 v1 = *reinterpret_cast<const float4*>(rp + ks * 32 + 4);
            bf16x8 a;
            a[0] = f2bf(v0.x); a[1] = f2bf(v0.y); a[2] = f2bf(v0.z); a[3] = f2bf(v0.w);
            a[4] = f2bf(v1.x); a[5] = f2bf(v1.y); a[6] = f2bf(v1.z); a[7] = f2bf(v1.w);
            afr[rt][ks] = a;
        }
    }

    f32x4 acc[2][8] = {};
#pragma unroll
    for (int cb = 0; cb < 8; ++cb) {
        const unsigned short* bp = Wswz + ((size_t)(cb * 4) * 64 + lane) * 8;
        bf16x8 bfr[4];
#pragma unroll
        for (int ks = 0; ks < 4; ++ks)
            bfr[ks] = *reinterpret_cast<const bf16x8*>(bp + (size_t)ks * 512);
#pragma unroll
        for (int ks = 0; ks < 4; ++ks) {
            acc[0][cb] = __builtin_amdgcn_mfma_f32_16x16x32_bf16(afr[0][ks], bfr[ks], acc[0][cb], 0, 0, 0);
            acc[1][cb] = __builtin_amdgcn_mfma_f32_16x16x32_bf16(afr[1][ks], bfr[ks], acc[1][cb], 0, 0, 0);
        }
    }

    // attention-score block (16 cols: 0-7 a_src heads, 8-15 a_dst heads)
    f32x4 accs[2] = {};
#pragma unroll
    for (int ks = 0; ks < 4; ++ks) {
        const bf16x8 bs = *reinterpret_cast<const bf16x8*>(Sa + ((size_t)ks * 64 + lane) * 8);
        accs[0] = __builtin_amdgcn_mfma_f32_16x16x32_bf16(afr[0][ks], bs, accs[0], 0, 0, 0);
        accs[1] = __builtin_amdgcn_mfma_f32_16x16x32_bf16(afr[1][ks], bs, accs[1], 0, 0, 0);
    }

#pragma unroll
    for (int rt = 0; rt < 2; ++rt) {
#pragma unroll
        for (int reg = 0; reg < 4; ++reg) {
            const int row = rowbase + rt * 16 + kg * 4 + reg;
            if (row < n) {
                unsigned short* op = xpb + (size_t)row * 128 + lr;
#pragma unroll
                for (int cb = 0; cb < 8; ++cb)
                    op[cb * 16] = (unsigned short)f2bf(acc[rt][cb][reg]);
                if (lr < 8) a_src[row * 8 + lr] = accs[rt][reg];
                else        a_dst[row * 8 + (lr - 8)] = accs[rt][reg];
            }
        }
    }
}

// ---------------- P1: coarse-bucket histogram per block ----------------
__global__ __launch_bounds__(256) void p1_hist(
    const int* __restrict__ ei, int* __restrict__ M, int E, int N, int nblk)
{
    __shared__ int h[NBUCK];
    const int tid = threadIdx.x;
    for (int k = tid; k < NBUCK; k += 256) h[k] = 0;
    __syncthreads();

    const int tot = E + N;
    const int base = blockIdx.x * IPB;
    const int lim = (base + IPB < tot) ? base + IPB : tot;
    for (int j = base + tid; j < lim; j += 256) {
        const int d = (j < E) ? ei[E + j] : (j - E);
        atomicAdd(&h[d >> BSHIFT], 1);
    }
    __syncthreads();
    for (int k = tid; k < NBUCK; k += 256)
        M[(size_t)k * nblk + blockIdx.x] = h[k];
}

// ---------------- P2a: per-bucket exclusive scan of M over blocks ------------
__global__ __launch_bounds__(256) void p2a_colscan(
    int* __restrict__ M, int* __restrict__ col_total, int nblk)
{
    const int b    = blockIdx.x;
    const int tid  = threadIdx.x;
    const int lane = tid & 63;
    const int wid  = tid >> 6;
    __shared__ int wsum[4];

    int carry = 0;
    for (int base = 0; base < nblk; base += 256) {
        const int idx = base + tid;
        const int v = (idx < nblk) ? M[(size_t)b * nblk + idx] : 0;
        int ws = v;
#pragma unroll
        for (int off = 1; off < 64; off <<= 1) {
            const int t = __shfl_up(ws, off);
            if (lane >= off) ws += t;
        }
        if (lane == 63) wsum[wid] = ws;
        __syncthreads();
        int woff = 0;
        for (int w2 = 0; w2 < wid; ++w2) woff += wsum[w2];
        const int alltot = wsum[0] + wsum[1] + wsum[2] + wsum[3];
        if (idx < nblk) M[(size_t)b * nblk + idx] = carry + woff + ws - v;
        carry += alltot;
        __syncthreads();
    }
    if (tid == 0) col_total[b] = carry;
}

// ---------------- P2b: scan col_total -> bucket_ptr; row_ptr[N]=tot ----------
__global__ __launch_bounds__(NBUCK) void p2b_bucketptr(
    const int* __restrict__ col_total, int* __restrict__ bucket_ptr,
    int* __restrict__ row_ptr, int N)
{
    const int tid  = threadIdx.x;
    const int lane = tid & 63;
    const int wid  = tid >> 6;
    __shared__ int wsum[4];

    const int v = col_total[tid];
    int ws = v;
#pragma unroll
    for (int off = 1; off < 64; off <<= 1) {
        const int t = __shfl_up(ws, off);
        if (lane >= off) ws += t;
    }
    if (lane == 63) wsum[wid] = ws;
    __syncthreads();
    int woff = 0;
    for (int w2 = 0; w2 < wid; ++w2) woff += wsum[w2];
    const int excl = woff + ws - v;
    bucket_ptr[tid] = excl;
    if (tid == NBUCK - 1) {
        bucket_ptr[NBUCK] = excl + v;
        row_ptr[N] = excl + v;
    }
}

// ---------------- P3: scatter packed (src | dl<<17) into bucket segments -----
__global__ __launch_bounds__(256) void p3_scatter(
    const int* __restrict__ ei, const int* __restrict__ M,
    const int* __restrict__ bucket_ptr, int* __restrict__ pairs,
    int E, int N, int nblk)
{
    __shared__ int lcnt[NBUCK];
    const int tid = threadIdx.x;
    for (int k = tid; k < NBUCK; k += 256) lcnt[k] = 0;
    __syncthreads();

    const int tot = E + N;
    const int base = blockIdx.x * IPB;
    const int lim = (base + IPB < tot) ? base + IPB : tot;
    for (int j = base + tid; j < lim; j += 256) {
        int s, d;
        if (j < E) { s = ei[j]; d = ei[E + j]; }
        else       { s = j - E; d = s; }
        const int b = d >> BSHIFT;
        const int r = atomicAdd(&lcnt[b], 1);
        const int pos = bucket_ptr[b] + M[(size_t)b * nblk + blockIdx.x] + r;
        pairs[pos] = s | ((d & (BNODES - 1)) << 17);
    }
}

// ---------------- P4: per-bucket row_ptr + csr scatter ----------------
__global__ __launch_bounds__(256) void p4_finalize(
    const int* __restrict__ pairs, const int* __restrict__ bucket_ptr,
    int* __restrict__ row_ptr, int* __restrict__ csr_src, int N)
{
    const int b     = blockIdx.x;
    const int node0 = b << BSHIFT;
    const int beg   = bucket_ptr[b];
    const int end   = bucket_ptr[b + 1];
    const int tid   = threadIdx.x;
    const int lane  = tid & 63;
    const int wid   = tid >> 6;

    __shared__ int hist[BNODES];
    __shared__ int exc[BNODES];
    __shared__ int cnt2[BNODES];
    __shared__ int wsum[4];

    for (int k = tid; k < BNODES; k += 256) { hist[k] = 0; cnt2[k] = 0; }
    __syncthreads();

    for (int i = beg + tid; i < end; i += 256)
        atomicAdd(&hist[pairs[i] >> 17], 1);
    __syncthreads();

    const int a0 = hist[2 * tid];
    const int a1 = hist[2 * tid + 1];
    const int s  = a0 + a1;
    int ws = s;
#pragma unroll
    for (int off = 1; off < 64; off <<= 1) {
        const int t = __shfl_up(ws, off);
        if (lane >= off) ws += t;
    }
    if (lane == 63) wsum[wid] = ws;
    __syncthreads();
    int woff = 0;
    for (int w2 = 0; w2 < wid; ++w2) woff += wsum[w2];
    const int e0 = woff + ws - s;
    exc[2 * tid]     = e0;
    exc[2 * tid + 1] = e0 + a0;
    __syncthreads();

    for (int k = tid; k < BNODES; k += 256) {
        const int node = node0 + k;
        if (node < N) row_ptr[node] = beg + exc[k];
    }
    for (int i = beg + tid; i < end; i += 256) {
        const int v  = pairs[i];
        const int dl = v >> 17;
        const int r  = atomicAdd(&cnt2[dl], 1);
        csr_src[beg + exc[dl] + r] = v & 0x1FFFF;
    }
}

// ---------------- K5: softmax aggregation, unstabilized exp, unroll x4 -------
__global__ __launch_bounds__(256) void k5_aggregate(
    const unsigned short* __restrict__ xpb, const float* __restrict__ a_src,
    const float* __restrict__ a_dst, const int* __restrict__ row_ptr,
    const int* __restrict__ csr_src, const float* __restrict__ b_gat,
    float* __restrict__ z, unsigned int* __restrict__ zb, int n)
{
    const int wave = blockIdx.x * 4 + __builtin_amdgcn_readfirstlane(threadIdx.x >> 6);
    if (wave >= n) return;
    const int lane = threadIdx.x & 63;
    const int d = wave;
    const int beg = row_ptr[d];
    const int end = row_ptr[d + 1];
    const int h = lane >> 3;
    const float adst = a_dst[d * 8 + h];
    const int co = 2 * lane;

    float l0 = 0.f, l1 = 0.f;
    float ax0 = 0.f, ay0 = 0.f, ax1 = 0.f, ay1 = 0.f;

    int i = beg;
    for (; i + 4 <= end; i += 4) {
        const int s0 = csr_src[i + 0];
        const int s1 = csr_src[i + 1];
        const int s2 = csr_src[i + 2];
        const int s3 = csr_src[i + 3];
        const unsigned int xv0 = *reinterpret_cast<const unsigned int*>(xpb + (size_t)s0 * 128 + co);
        const unsigned int xv1 = *reinterpret_cast<const unsigned int*>(xpb + (size_t)s1 * 128 + co);
        const unsigned int xv2 = *reinterpret_cast<const unsigned int*>(xpb + (size_t)s2 * 128 + co);
        const unsigned int xv3 = *reinterpret_cast<const unsigned int*>(xpb + (size_t)s3 * 128 + co);
        float v0 = a_src[s0 * 8 + h] + adst;
        float v1 = a_src[s1 * 8 + h] + adst;
        float v2 = a_src[s2 * 8 + h] + adst;
        float v3 = a_src[s3 * 8 + h] + adst;
        v0 = (v0 > 0.f) ? v0 : 0.2f * v0;
        v1 = (v1 > 0.f) ? v1 : 0.2f * v1;
        v2 = (v2 > 0.f) ? v2 : 0.2f * v2;
        v3 = (v3 > 0.f) ? v3 : 0.2f * v3;
        const float p0 = __expf(v0);
        const float p1 = __expf(v1);
        const float p2 = __expf(v2);
        const float p3 = __expf(v3);
        l0 += p0 + p1;
        l1 += p2 + p3;
        ax0 = fmaf(p0, __uint_as_float(xv0 << 16), ax0);
        ay0 = fmaf(p0, __uint_as_float(xv0 & 0xffff0000u), ay0);
        ax1 = fmaf(p1, __uint_as_float(xv1 << 16), ax1);
        ay1 = fmaf(p1, __uint_as_float(xv1 & 0xffff0000u), ay1);
        ax0 = fmaf(p2, __uint_as_float(xv2 << 16), ax0);
        ay0 = fmaf(p2, __uint_as_float(xv2 & 0xffff0000u), ay0);
        ax1 = fmaf(p3, __uint_as_float(xv3 << 16), ax1);
        ay1 = fmaf(p3, __uint_as_float(xv3 & 0xffff0000u), ay1);
    }
    for (; i < end; ++i) {
        const int s = csr_src[i];
        const unsigned int xv = *reinterpret_cast<const unsigned int*>(xpb + (size_t)s * 128 + co);
        float v = a_src[s * 8 + h] + adst;
        v = (v > 0.f) ? v : 0.2f * v;
        const float p = __expf(v);
        l0 += p;
        ax0 = fmaf(p, __uint_as_float(xv << 16), ax0);
        ay0 = fmaf(p, __uint_as_float(xv & 0xffff0000u), ay0);
    }

    const float inv = 1.0f / (l0 + l1 + 1e-16f);
    const float2 bg = *reinterpret_cast<const float2*>(&b_gat[co]);
    float2 o;
    o.x = (ax0 + ax1) * inv + bg.x;
    o.y = (ay0 + ay1) * inv + bg.y;
    *reinterpret_cast<float2*>(&z[(size_t)d * 128 + co]) = o;
    const unsigned int pk = ((unsigned int)(unsigned short)f2bf(o.y) << 16) |
                            (unsigned int)(unsigned short)f2bf(o.x);
    zb[(size_t)d * 64 + lane] = pk;
}

// ---------------- G2: z1 = z@W1+b1, z2 = z@W2+b2 via MFMA (A from zb) -------
__global__ __launch_bounds__(256) void g2_mfma_fc(
    const unsigned int* __restrict__ zb,
    const unsigned short* __restrict__ S1, const unsigned short* __restrict__ S2,
    const float* __restrict__ b1, const float* __restrict__ b2,
    float* __restrict__ z1, float* __restrict__ z2, int n)
{
    const int wid  = __builtin_amdgcn_readfirstlane(threadIdx.x >> 6);
    const int lane = threadIdx.x & 63;
    const int lr   = lane & 15;
    const int kg   = lane >> 4;
    const int rowbase = blockIdx.x * 128 + wid * 32;

    bf16x8 afr[2][4];
#pragma unroll
    for (int rt = 0; rt < 2; ++rt) {
        int row = rowbase + rt * 16 + lr;
        row = (row < n) ? row : (n - 1);
        const unsigned short* rp = (const unsigned short*)(zb + (size_t)row * 64) + kg * 8;
#pragma unroll
        for (int ks = 0; ks < 4; ++ks)
            afr[rt][ks] = *reinterpret_cast<const bf16x8*>(rp + ks * 32);
    }

    f32x4 acc1[2][8] = {};
    f32x4 acc2[2][8] = {};
#pragma unroll
    for (int cb = 0; cb < 8; ++cb) {
        const unsigned short* bp1 = S1 + ((size_t)(cb * 4) * 64 + lane) * 8;
        const unsigned short* bp2 = S2 + ((size_t)(cb * 4) * 64 + lane) * 8;
        bf16x8 f1[4], f2v[4];
#pragma unroll
        for (int ks = 0; ks < 4; ++ks) {
            f1[ks]  = *reinterpret_cast<const bf16x8*>(bp1 + (size_t)ks * 512);
            f2v[ks] = *reinterpret_cast<const bf16x8*>(bp2 + (size_t)ks * 512);
        }
#pragma unroll
        for (int ks = 0; ks < 4; ++ks) {
            acc1[0][cb] = __builtin_amdgcn_mfma_f32_16x16x32_bf16(afr[0][ks], f1[ks],  acc1[0][cb], 0, 0, 0);
            acc1[1][cb] = __builtin_amdgcn_mfma_f32_16x16x32_bf16(afr[1][ks], f1[ks],  acc1[1][cb], 0, 0, 0);
            acc2[0][cb] = __builtin_amdgcn_mfma_f32_16x16x32_bf16(afr[0][ks], f2v[ks], acc2[0][cb], 0, 0, 0);
            acc2[1][cb] = __builtin_amdgcn_mfma_f32_16x16x32_bf16(afr[1][ks], f2v[ks], acc2[1][cb], 0, 0, 0);
        }
    }

    float bb1[8], bb2[8];
#pragma unroll
    for (int cb = 0; cb < 8; ++cb) { bb1[cb] = b1[cb * 16 + lr]; bb2[cb] = b2[cb * 16 + lr]; }

#pragma unroll
    for (int rt = 0; rt < 2; ++rt) {
#pragma unroll
        for (int reg = 0; reg < 4; ++reg) {
            const int row = rowbase + rt * 16 + kg * 4 + reg;
            if (row < n) {
                float* o1 = z1 + (size_t)row * 128 + lr;
                float* o2 = z2 + (size_t)row * 128 + lr;
#pragma unroll
                for (int cb = 0; cb < 8; ++cb) {
                    o1[cb * 16] = acc1[rt][cb][reg] + bb1[cb];
                    o2[cb * 16] = acc2[rt][cb][reg] + bb2[cb];
                }
            }
        }
    }
}

// ---------------------------------------------------------------------------
extern "C" void kernel_launch(void* const* d_in, const int* in_sizes, int n_in,
                              void* d_out, int out_size, void* d_ws, size_t ws_size,
                              hipStream_t stream)
{
    const float* x       = (const float*)d_in[0];
    const int*   ei      = (const int*)  d_in[1];
    const float* W_gat   = (const float*)d_in[2];
    const float* att_src = (const float*)d_in[3];
    const float* att_dst = (const float*)d_in[4];
    const float* b_gat   = (const float*)d_in[5];
    const float* W_fc1   = (const float*)d_in[6];
    const float* b_fc1   = (const float*)d_in[7];
    const float* W_fc2   = (const float*)d_in[8];
    const float* b_fc2   = (const float*)d_in[9];

    const int N = in_sizes[0] / 128;
    const int E = in_sizes[1] / 2;
    const int tot = E + N;
    const int nblk = (tot + IPB - 1) / IPB;
    const int nbuck_used = (N + BNODES - 1) >> BSHIFT;

    char* w = (char*)d_ws;
    unsigned short* xpb = (unsigned short*)w;  w += (size_t)N * 128 * 2;
    unsigned int* zb = (unsigned int*)w;       w += (size_t)N * 64 * 4;
    float* a_src  = (float*)w;  w += (size_t)N * 8 * 4;
    float* a_dst  = (float*)w;  w += (size_t)N * 8 * 4;
    int* row_ptr  = (int*)w;    w += (size_t)(N + 1) * 4;
    w = (char*)(((size_t)w + 15) & ~(size_t)15);
    unsigned short* S0 = (unsigned short*)w; w += 16384 * 2;
    unsigned short* S1 = (unsigned short*)w; w += 16384 * 2;
    unsigned short* S2 = (unsigned short*)w; w += 16384 * 2;
    unsigned short* Sa = (unsigned short*)w; w += 2048 * 2;
    int* M          = (int*)w;  w += (size_t)nblk * NBUCK * 4;
    int* col_total  = (int*)w;  w += NBUCK * 4;
    int* bucket_ptr = (int*)w;  w += (NBUCK + 1) * 4;
    w = (char*)(((size_t)w + 15) & ~(size_t)15);
    int* pairs    = (int*)w;    w += (size_t)tot * 4;
    int* csr_src  = (int*)w;    w += (size_t)tot * 4;

    float* z  = (float*)d_out;
    float* z1 = z  + (size_t)N * 128;
    float* z2 = z1 + (size_t)N * 128;

    k0_swizzle<<<(3 * 2048 + 256 + 255) / 256, 256, 0, stream>>>(
        W_gat, W_fc1, W_fc2, att_src, att_dst, S0, S1, S2, Sa);

    g1_mfma<<<(N + 127) / 128, 256, 0, stream>>>(x, S0, Sa, xpb, a_src, a_dst, N);

    p1_hist<<<nblk, 256, 0, stream>>>(ei, M, E, N, nblk);
    p2a_colscan<<<NBUCK, 256, 0, stream>>>(M, col_total, nblk);
    p2b_bucketptr<<<1, NBUCK, 0, stream>>>(col_total, bucket_ptr, row_ptr, N);
    p3_scatter<<<nblk, 256, 0, stream>>>(ei, M, bucket_ptr, pairs, E, N, nblk);
    p4_finalize<<<nbuck_used, 256, 0, stream>>>(pairs, bucket_ptr, row_ptr, csr_src, N);

    k5_aggregate<<<(N + 3) / 4, 256, 0, stream>>>(xpb, a_src, a_dst, row_ptr, csr_src,
                                                  b_gat, z, zb, N);

    g2_mfma_fc<<<(N + 127) / 128, 256, 0, stream>>>(zb, S1, S2, b_fc1, b_fc2, z1, z2, N);
}

// Round 7
// 204.809 us; speedup vs baseline: 3.0502x; 1.0680x over previous
//
#include <hip/hip_runtime.h>
#include <hip/hip_bf16.h>

// ---------------------------------------------------------------------------
// GAT + 2 FC layers, MFMA + atomic-free CSR build (7 launches).
//   K0  : swizzle W_gat/W_fc1/W_fc2 (+WA att matrix) to MFMA B-frag order;
//         zero col_total
//   G1P1: fused [xp = x@W_gat MFMA + scores] and [coarse bucket histogram]
//   P2a : per-bucket scan of M over blocks, + in-block scan of col_total ->
//         bucket bases folded into M; writes bucket_ptr, row_ptr[N]
//   P3  : scatter packed (src|dl<<17) into bucket segments (LDS rank)
//   P4  : per-bucket LDS hist over 512 dsts -> row_ptr + csr_src
//   K5  : per-dst softmax aggregation, unstabilized exp, unroll x8 predicated
//   G2  : z1 = z@W_fc1+b1, z2 = z@W_fc2+b2 (bf16 MFMA, A from zb)
// ---------------------------------------------------------------------------

#define NBUCK  256
#define BSHIFT 9
#define BNODES 512
#define IPB    8192

typedef __attribute__((ext_vector_type(8))) short bf16x8;
typedef __attribute__((ext_vector_type(4))) float f32x4;

static __device__ __forceinline__ short f2bf(float f) {
    __hip_bfloat16 h = __float2bfloat16(f);
    return *reinterpret_cast<short*>(&h);
}

// ---------------- K0: weight swizzles + WA precompute + col_total zero -------
__global__ __launch_bounds__(256) void k0_swizzle(
    const float* __restrict__ W0, const float* __restrict__ W1,
    const float* __restrict__ W2, const float* __restrict__ att_s,
    const float* __restrict__ att_d, unsigned short* __restrict__ S0,
    unsigned short* __restrict__ S1, unsigned short* __restrict__ S2,
    unsigned short* __restrict__ Sa, int* __restrict__ col_total)
{
    const int t = blockIdx.x * 256 + threadIdx.x;
    if (t < NBUCK) col_total[t] = 0;
    if (t < 3 * 2048) {
        const int m = t >> 11;
        const int r = t & 2047;
        const int tile = r >> 6;          // cb*4 + ks
        const int l    = r & 63;
        const int ks   = tile & 3;
        const int cb   = tile >> 2;
        const int c    = cb * 16 + (l & 15);
        const int kb   = ks * 32 + (l >> 4) * 8;
        const float* W = (m == 0) ? W0 : (m == 1) ? W1 : W2;
        unsigned short* S = (m == 0) ? S0 : (m == 1) ? S1 : S2;
        unsigned short* dst = S + ((size_t)tile * 64 + l) * 8;
#pragma unroll
        for (int j = 0; j < 8; ++j)
            dst[j] = (unsigned short)f2bf(W[(kb + j) * 128 + c]);
    } else if (t < 3 * 2048 + 256) {
        const int r  = t - 3 * 2048;
        const int ks = r >> 6;
        const int l  = r & 63;
        const int hp = l & 15;
        const int h  = hp & 7;
        const float* av = (hp < 8) ? (att_s + h * 16) : (att_d + h * 16);
        unsigned short* dst = Sa + ((size_t)ks * 64 + l) * 8;
#pragma unroll
        for (int j = 0; j < 8; ++j) {
            const int k = ks * 32 + (l >> 4) * 8 + j;
            float acc = 0.f;
#pragma unroll
            for (int u = 0; u < 16; ++u)
                acc += W0[k * 128 + h * 16 + u] * av[u];
            dst[j] = (unsigned short)f2bf(acc);
        }
    }
}

// ---------------- G1P1: fused GEMM+scores | bucket histogram ----------------
__global__ __launch_bounds__(256) void g1p1(
    const float* __restrict__ x, const unsigned short* __restrict__ Wswz,
    const unsigned short* __restrict__ Sa, unsigned short* __restrict__ xpb,
    float* __restrict__ a_src, float* __restrict__ a_dst,
    const int* __restrict__ ei, int* __restrict__ M, int* __restrict__ col_total,
    int n, int E, int g1b, int nblk)
{
    if ((int)blockIdx.x < g1b) {
        // ---- G1 part ----
        const int wid  = __builtin_amdgcn_readfirstlane(threadIdx.x >> 6);
        const int lane = threadIdx.x & 63;
        const int lr   = lane & 15;
        const int kg   = lane >> 4;
        const int rowbase = blockIdx.x * 128 + wid * 32;

        bf16x8 afr[2][4];
#pragma unroll
        for (int rt = 0; rt < 2; ++rt) {
            int row = rowbase + rt * 16 + lr;
            row = (row < n) ? row : (n - 1);
            const float* rp = x + (size_t)row * 128 + kg * 8;
#pragma unroll
            for (int ks = 0; ks < 4; ++ks) {
                const float4 v0 = *reinterpret_cast<const float4*>(rp + ks * 32);
                const float4 v1 = *reinterpret_cast<const float4*>(rp + ks * 32 + 4);
                bf16x8 a;
                a[0] = f2bf(v0.x); a[1] = f2bf(v0.y); a[2] = f2bf(v0.z); a[3] = f2bf(v0.w);
                a[4] = f2bf(v1.x); a[5] = f2bf(v1.y); a[6] = f2bf(v1.z); a[7] = f2bf(v1.w);
                afr[rt][ks] = a;
            }
        }

        f32x4 acc[2][8] = {};
#pragma unroll
        for (int cb = 0; cb < 8; ++cb) {
            const unsigned short* bp = Wswz + ((size_t)(cb * 4) * 64 + lane) * 8;
            bf16x8 bfr[4];
#pragma unroll
            for (int ks = 0; ks < 4; ++ks)
                bfr[ks] = *reinterpret_cast<const bf16x8*>(bp + (size_t)ks * 512);
#pragma unroll
            for (int ks = 0; ks < 4; ++ks) {
                acc[0][cb] = __builtin_amdgcn_mfma_f32_16x16x32_bf16(afr[0][ks], bfr[ks], acc[0][cb], 0, 0, 0);
                acc[1][cb] = __builtin_amdgcn_mfma_f32_16x16x32_bf16(afr[1][ks], bfr[ks], acc[1][cb], 0, 0, 0);
            }
        }

        f32x4 accs[2] = {};
#pragma unroll
        for (int ks = 0; ks < 4; ++ks) {
            const bf16x8 bs = *reinterpret_cast<const bf16x8*>(Sa + ((size_t)ks * 64 + lane) * 8);
            accs[0] = __builtin_amdgcn_mfma_f32_16x16x32_bf16(afr[0][ks], bs, accs[0], 0, 0, 0);
            accs[1] = __builtin_amdgcn_mfma_f32_16x16x32_bf16(afr[1][ks], bs, accs[1], 0, 0, 0);
        }

#pragma unroll
        for (int rt = 0; rt < 2; ++rt) {
#pragma unroll
            for (int reg = 0; reg < 4; ++reg) {
                const int row = rowbase + rt * 16 + kg * 4 + reg;
                if (row < n) {
                    unsigned short* op = xpb + (size_t)row * 128 + lr;
#pragma unroll
                    for (int cb = 0; cb < 8; ++cb)
                        op[cb * 16] = (unsigned short)f2bf(acc[rt][cb][reg]);
                    if (lr < 8) a_src[row * 8 + lr] = accs[rt][reg];
                    else        a_dst[row * 8 + (lr - 8)] = accs[rt][reg];
                }
            }
        }
    } else {
        // ---- P1 part ----
        __shared__ int h[NBUCK];
        const int pb  = blockIdx.x - g1b;
        const int tid = threadIdx.x;
        for (int k = tid; k < NBUCK; k += 256) h[k] = 0;
        __syncthreads();

        const int tot = E + n;
        const int base = pb * IPB;
        const int lim = (base + IPB < tot) ? base + IPB : tot;
        for (int j = base + tid; j < lim; j += 256) {
            const int d = (j < E) ? ei[E + j] : (j - E);
            atomicAdd(&h[d >> BSHIFT], 1);
        }
        __syncthreads();
        for (int k = tid; k < NBUCK; k += 256) {
            M[(size_t)k * nblk + pb] = h[k];
            if (h[k]) atomicAdd(&col_total[k], h[k]);
        }
    }
}

// ---------------- P2a: bucket bases + per-bucket scan of M ----------------
__global__ __launch_bounds__(256) void p2a_colscan(
    int* __restrict__ M, const int* __restrict__ col_total,
    int* __restrict__ bucket_ptr, int* __restrict__ row_ptr, int nblk, int N)
{
    const int b    = blockIdx.x;
    const int tid  = threadIdx.x;
    const int lane = tid & 63;
    const int wid  = tid >> 6;
    __shared__ int wsum[4];
    __shared__ int sbase;

    // in-block exclusive scan of col_total[256] -> base for this bucket
    const int v0 = col_total[tid];
    int ws0 = v0;
#pragma unroll
    for (int off = 1; off < 64; off <<= 1) {
        const int t = __shfl_up(ws0, off);
        if (lane >= off) ws0 += t;
    }
    if (lane == 63) wsum[wid] = ws0;
    __syncthreads();
    int woff0 = 0;
    for (int w2 = 0; w2 < wid; ++w2) woff0 += wsum[w2];
    const int excl0 = woff0 + ws0 - v0;
    if (tid == b) sbase = excl0;
    if (b == NBUCK - 1 && tid == NBUCK - 1) {
        bucket_ptr[NBUCK] = excl0 + v0;
        row_ptr[N] = excl0 + v0;
    }
    __syncthreads();
    const int base = sbase;
    if (tid == 0) bucket_ptr[b] = base;
    __syncthreads();

    // scan M row, folding in base
    int carry = base;
    for (int bb = 0; bb < nblk; bb += 256) {
        const int idx = bb + tid;
        const int v = (idx < nblk) ? M[(size_t)b * nblk + idx] : 0;
        int ws = v;
#pragma unroll
        for (int off = 1; off < 64; off <<= 1) {
            const int t = __shfl_up(ws, off);
            if (lane >= off) ws += t;
        }
        if (lane == 63) wsum[wid] = ws;
        __syncthreads();
        int woff = 0;
        for (int w2 = 0; w2 < wid; ++w2) woff += wsum[w2];
        const int alltot = wsum[0] + wsum[1] + wsum[2] + wsum[3];
        if (idx < nblk) M[(size_t)b * nblk + idx] = carry + woff + ws - v;
        carry += alltot;
        __syncthreads();
    }
}

// ---------------- P3: scatter packed (src | dl<<17) into bucket segments -----
__global__ __launch_bounds__(256) void p3_scatter(
    const int* __restrict__ ei, const int* __restrict__ M,
    int* __restrict__ pairs, int E, int N, int nblk)
{
    __shared__ int lcnt[NBUCK];
    const int tid = threadIdx.x;
    for (int k = tid; k < NBUCK; k += 256) lcnt[k] = 0;
    __syncthreads();

    const int tot = E + N;
    const int base = blockIdx.x * IPB;
    const int lim = (base + IPB < tot) ? base + IPB : tot;
    for (int j = base + tid; j < lim; j += 256) {
        int s, d;
        if (j < E) { s = ei[j]; d = ei[E + j]; }
        else       { s = j - E; d = s; }
        const int b = d >> BSHIFT;
        const int r = atomicAdd(&lcnt[b], 1);
        const int pos = M[(size_t)b * nblk + blockIdx.x] + r;
        pairs[pos] = s | ((d & (BNODES - 1)) << 17);
    }
}

// ---------------- P4: per-bucket row_ptr + csr scatter ----------------
__global__ __launch_bounds__(256) void p4_finalize(
    const int* __restrict__ pairs, const int* __restrict__ bucket_ptr,
    int* __restrict__ row_ptr, int* __restrict__ csr_src, int N)
{
    const int b     = blockIdx.x;
    const int node0 = b << BSHIFT;
    const int beg   = bucket_ptr[b];
    const int end   = bucket_ptr[b + 1];
    const int tid   = threadIdx.x;
    const int lane  = tid & 63;
    const int wid   = tid >> 6;

    __shared__ int hist[BNODES];
    __shared__ int exc[BNODES];
    __shared__ int cnt2[BNODES];
    __shared__ int wsum[4];

    for (int k = tid; k < BNODES; k += 256) { hist[k] = 0; cnt2[k] = 0; }
    __syncthreads();

    for (int i = beg + tid; i < end; i += 256)
        atomicAdd(&hist[pairs[i] >> 17], 1);
    __syncthreads();

    const int a0 = hist[2 * tid];
    const int a1 = hist[2 * tid + 1];
    const int s  = a0 + a1;
    int ws = s;
#pragma unroll
    for (int off = 1; off < 64; off <<= 1) {
        const int t = __shfl_up(ws, off);
        if (lane >= off) ws += t;
    }
    if (lane == 63) wsum[wid] = ws;
    __syncthreads();
    int woff = 0;
    for (int w2 = 0; w2 < wid; ++w2) woff += wsum[w2];
    const int e0 = woff + ws - s;
    exc[2 * tid]     = e0;
    exc[2 * tid + 1] = e0 + a0;
    __syncthreads();

    for (int k = tid; k < BNODES; k += 256) {
        const int node = node0 + k;
        if (node < N) row_ptr[node] = beg + exc[k];
    }
    for (int i = beg + tid; i < end; i += 256) {
        const int v  = pairs[i];
        const int dl = v >> 17;
        const int r  = atomicAdd(&cnt2[dl], 1);
        csr_src[beg + exc[dl] + r] = v & 0x1FFFF;
    }
}

// ---------------- K5: softmax aggregation, unroll x8 predicated --------------
__global__ __launch_bounds__(256) void k5_aggregate(
    const unsigned short* __restrict__ xpb, const float* __restrict__ a_src,
    const float* __restrict__ a_dst, const int* __restrict__ row_ptr,
    const int* __restrict__ csr_src, const float* __restrict__ b_gat,
    float* __restrict__ z, unsigned int* __restrict__ zb, int n)
{
    const int wave = blockIdx.x * 4 + __builtin_amdgcn_readfirstlane(threadIdx.x >> 6);
    if (wave >= n) return;
    const int lane = threadIdx.x & 63;
    const int d = wave;
    const int beg = row_ptr[d];
    const int end = row_ptr[d + 1];
    const int h = lane >> 3;
    const float adst = a_dst[d * 8 + h];
    const int co = 2 * lane;

    float l0 = 0.f, l1 = 0.f;
    float ax0 = 0.f, ay0 = 0.f, ax1 = 0.f, ay1 = 0.f;

    for (int i = beg; i < end; i += 8) {
        int ss[8];
        unsigned int xv[8];
        float pv[8];
#pragma unroll
        for (int j = 0; j < 8; ++j) {
            const int idx = i + j;
            ss[j] = csr_src[(idx < end) ? idx : (end - 1)];
        }
#pragma unroll
        for (int j = 0; j < 8; ++j)
            xv[j] = *reinterpret_cast<const unsigned int*>(xpb + (size_t)ss[j] * 128 + co);
#pragma unroll
        for (int j = 0; j < 8; ++j) {
            float v = a_src[ss[j] * 8 + h] + adst;
            v = (v > 0.f) ? v : 0.2f * v;
            const float e = __expf(v);
            pv[j] = (i + j < end) ? e : 0.f;
        }
#pragma unroll
        for (int j = 0; j < 8; ++j) {
            const float cx = __uint_as_float(xv[j] << 16);
            const float cy = __uint_as_float(xv[j] & 0xffff0000u);
            if (j & 1) {
                l1 += pv[j];
                ax1 = fmaf(pv[j], cx, ax1);
                ay1 = fmaf(pv[j], cy, ay1);
            } else {
                l0 += pv[j];
                ax0 = fmaf(pv[j], cx, ax0);
                ay0 = fmaf(pv[j], cy, ay0);
            }
        }
    }

    const float inv = 1.0f / (l0 + l1 + 1e-16f);
    const float2 bg = *reinterpret_cast<const float2*>(&b_gat[co]);
    float2 o;
    o.x = (ax0 + ax1) * inv + bg.x;
    o.y = (ay0 + ay1) * inv + bg.y;
    *reinterpret_cast<float2*>(&z[(size_t)d * 128 + co]) = o;
    const unsigned int pk = ((unsigned int)(unsigned short)f2bf(o.y) << 16) |
                            (unsigned int)(unsigned short)f2bf(o.x);
    zb[(size_t)d * 64 + lane] = pk;
}

// ---------------- G2: z1 = z@W1+b1, z2 = z@W2+b2 via MFMA (A from zb) -------
__global__ __launch_bounds__(256) void g2_mfma_fc(
    const unsigned int* __restrict__ zb,
    const unsigned short* __restrict__ S1, const unsigned short* __restrict__ S2,
    const float* __restrict__ b1, const float* __restrict__ b2,
    float* __restrict__ z1, float* __restrict__ z2, int n)
{
    const int wid  = __builtin_amdgcn_readfirstlane(threadIdx.x >> 6);
    const int lane = threadIdx.x & 63;
    const int lr   = lane & 15;
    const int kg   = lane >> 4;
    const int rowbase = blockIdx.x * 128 + wid * 32;

    bf16x8 afr[2][4];
#pragma unroll
    for (int rt = 0; rt < 2; ++rt) {
        int row = rowbase + rt * 16 + lr;
        row = (row < n) ? row : (n - 1);
        const unsigned short* rp = (const unsigned short*)(zb + (size_t)row * 64) + kg * 8;
#pragma unroll
        for (int ks = 0; ks < 4; ++ks)
            afr[rt][ks] = *reinterpret_cast<const bf16x8*>(rp + ks * 32);
    }

    f32x4 acc1[2][8] = {};
    f32x4 acc2[2][8] = {};
#pragma unroll
    for (int cb = 0; cb < 8; ++cb) {
        const unsigned short* bp1 = S1 + ((size_t)(cb * 4) * 64 + lane) * 8;
        const unsigned short* bp2 = S2 + ((size_t)(cb * 4) * 64 + lane) * 8;
        bf16x8 f1[4], f2v[4];
#pragma unroll
        for (int ks = 0; ks < 4; ++ks) {
            f1[ks]  = *reinterpret_cast<const bf16x8*>(bp1 + (size_t)ks * 512);
            f2v[ks] = *reinterpret_cast<const bf16x8*>(bp2 + (size_t)ks * 512);
        }
#pragma unroll
        for (int ks = 0; ks < 4; ++ks) {
            acc1[0][cb] = __builtin_amdgcn_mfma_f32_16x16x32_bf16(afr[0][ks], f1[ks],  acc1[0][cb], 0, 0, 0);
            acc1[1][cb] = __builtin_amdgcn_mfma_f32_16x16x32_bf16(afr[1][ks], f1[ks],  acc1[1][cb], 0, 0, 0);
            acc2[0][cb] = __builtin_amdgcn_mfma_f32_16x16x32_bf16(afr[0][ks], f2v[ks], acc2[0][cb], 0, 0, 0);
            acc2[1][cb] = __builtin_amdgcn_mfma_f32_16x16x32_bf16(afr[1][ks], f2v[ks], acc2[1][cb], 0, 0, 0);
        }
    }

    float bb1[8], bb2[8];
#pragma unroll
    for (int cb = 0; cb < 8; ++cb) { bb1[cb] = b1[cb * 16 + lr]; bb2[cb] = b2[cb * 16 + lr]; }

#pragma unroll
    for (int rt = 0; rt < 2; ++rt) {
#pragma unroll
        for (int reg = 0; reg < 4; ++reg) {
            const int row = rowbase + rt * 16 + kg * 4 + reg;
            if (row < n) {
                float* o1 = z1 + (size_t)row * 128 + lr;
                float* o2 = z2 + (size_t)row * 128 + lr;
#pragma unroll
                for (int cb = 0; cb < 8; ++cb) {
                    o1[cb * 16] = acc1[rt][cb][reg] + bb1[cb];
                    o2[cb * 16] = acc2[rt][cb][reg] + bb2[cb];
                }
            }
        }
    }
}

// ---------------------------------------------------------------------------
extern "C" void kernel_launch(void* const* d_in, const int* in_sizes, int n_in,
                              void* d_out, int out_size, void* d_ws, size_t ws_size,
                              hipStream_t stream)
{
    const float* x       = (const float*)d_in[0];
    const int*   ei      = (const int*)  d_in[1];
    const float* W_gat   = (const float*)d_in[2];
    const float* att_src = (const float*)d_in[3];
    const float* att_dst = (const float*)d_in[4];
    const float* b_gat   = (const float*)d_in[5];
    const float* W_fc1   = (const float*)d_in[6];
    const float* b_fc1   = (const float*)d_in[7];
    const float* W_fc2   = (const float*)d_in[8];
    const float* b_fc2   = (const float*)d_in[9];

    const int N = in_sizes[0] / 128;
    const int E = in_sizes[1] / 2;
    const int tot = E + N;
    const int nblk = (tot + IPB - 1) / IPB;
    const int nbuck_used = (N + BNODES - 1) >> BSHIFT;
    const int g1b = (N + 127) / 128;

    char* w = (char*)d_ws;
    unsigned short* xpb = (unsigned short*)w;  w += (size_t)N * 128 * 2;
    unsigned int* zb = (unsigned int*)w;       w += (size_t)N * 64 * 4;
    float* a_src  = (float*)w;  w += (size_t)N * 8 * 4;
    float* a_dst  = (float*)w;  w += (size_t)N * 8 * 4;
    int* row_ptr  = (int*)w;    w += (size_t)(N + 1) * 4;
    w = (char*)(((size_t)w + 15) & ~(size_t)15);
    unsigned short* S0 = (unsigned short*)w; w += 16384 * 2;
    unsigned short* S1 = (unsigned short*)w; w += 16384 * 2;
    unsigned short* S2 = (unsigned short*)w; w += 16384 * 2;
    unsigned short* Sa = (unsigned short*)w; w += 2048 * 2;
    int* M          = (int*)w;  w += (size_t)nblk * NBUCK * 4;
    int* col_total  = (int*)w;  w += NBUCK * 4;
    int* bucket_ptr = (int*)w;  w += (NBUCK + 1) * 4;
    w = (char*)(((size_t)w + 15) & ~(size_t)15);
    int* pairs    = (int*)w;    w += (size_t)tot * 4;
    int* csr_src  = (int*)w;    w += (size_t)tot * 4;

    float* z  = (float*)d_out;
    float* z1 = z  + (size_t)N * 128;
    float* z2 = z1 + (size_t)N * 128;

    k0_swizzle<<<(3 * 2048 + 256 + 255) / 256, 256, 0, stream>>>(
        W_gat, W_fc1, W_fc2, att_src, att_dst, S0, S1, S2, Sa, col_total);

    g1p1<<<g1b + nblk, 256, 0, stream>>>(x, S0, Sa, xpb, a_src, a_dst,
                                         ei, M, col_total, N, E, g1b, nblk);

    p2a_colscan<<<NBUCK, 256, 0, stream>>>(M, col_total, bucket_ptr, row_ptr, nblk, N);
    p3_scatter<<<nblk, 256, 0, stream>>>(ei, M, pairs, E, N, nblk);
    p4_finalize<<<nbuck_used, 256, 0, stream>>>(pairs, bucket_ptr, row_ptr, csr_src, N);

    k5_aggregate<<<(N + 3) / 4, 256, 0, stream>>>(xpb, a_src, a_dst, row_ptr, csr_src,
                                                  b_gat, z, zb, N);

    g2_mfma_fc<<<(N + 127) / 128, 256, 0, stream>>>(zb, S1, S2, b_fc1, b_fc2, z1, z2, N);
}